// Round 1
// baseline (474.409 us; speedup 1.0000x reference)
//
#include <hip/hip_runtime.h>
#include <math.h>

#define BATCH 16
#define LEN   160000
#define NFFT  512
#define HOP   128
#define NT    1251      // 1 + (160000+512-512)/128
#define NF    257
#define PADC  256
#define TWO_PI 6.28318530717958647692f

__device__ __forceinline__ int reflect_idx(int j) {
    j = j < 0 ? -j : j;
    j = j >= LEN ? 2*LEN - 2 - j : j;
    return j;
}

// In-LDS 512-point complex radix-2 DIT FFT, 256 threads.
// Input must be loaded bit-reversed; output is natural order.
// sign = -1 forward (exp(-i..)), +1 inverse (exp(+i..), unscaled).
__device__ __forceinline__ void fft512(float* sre, float* sim,
                                       const float* twc, const float* tws,
                                       float sign, int tid) {
    #pragma unroll
    for (int s = 1; s <= 9; ++s) {
        const int half = 1 << (s - 1);
        const int k  = tid & (half - 1);
        const int i0 = ((tid >> (s - 1)) << s) + k;
        const int i1 = i0 + half;
        const int m  = k << (9 - s);
        const float wr = twc[m];
        const float wi = sign * tws[m];
        const float ar = sre[i0], ai = sim[i0];
        const float br = sre[i1], bi = sim[i1];
        const float tr = br * wr - bi * wi;
        const float ti = br * wi + bi * wr;
        sre[i0] = ar + tr; sim[i0] = ai + ti;
        sre[i1] = ar - tr; sim[i1] = ai - ti;
        __syncthreads();
    }
}

// K1: STFT. grid (NT, B, 2): z=0 -> enhanced (complex spec), z=1 -> noisy (clamped mag)
__global__ __launch_bounds__(256) void stft_kernel(const float* __restrict__ enh,
                                                   const float* __restrict__ noi,
                                                   float2* __restrict__ e_spec,
                                                   float*  __restrict__ n_mag) {
    __shared__ float sre[512], sim[512], twc[256], tws[256];
    const int tid = threadIdx.x;
    const int t = blockIdx.x, b = blockIdx.y, z = blockIdx.z;
    const float* __restrict__ x = z ? noi : enh;

    const float ang = TWO_PI * (float)tid * (1.0f / 512.0f);
    twc[tid] = cosf(ang);
    tws[tid] = sinf(ang);

    const int base = t * HOP - PADC;
    #pragma unroll
    for (int q = 0; q < 2; ++q) {
        const int n = tid + q * 256;
        const int j = reflect_idx(base + n);
        const float w = 0.5f * (1.0f - cosf(TWO_PI * (float)n * (1.0f / 512.0f)));
        const float v = x[b * LEN + j] * w;
        const int r = __brev((unsigned)n) >> 23;
        sre[r] = v; sim[r] = 0.0f;
    }
    __syncthreads();
    fft512(sre, sim, twc, tws, -1.0f, tid);

    const int obase = (b * NT + t) * NF;
    if (z == 0) {
        e_spec[obase + tid] = make_float2(sre[tid], sim[tid]);
        if (tid == 0) e_spec[obase + 256] = make_float2(sre[256], sim[256]);
    } else {
        float re = sre[tid], im = sim[tid];
        n_mag[obase + tid] = fmaxf(sqrtf(re * re + im * im), 1e-6f);
        if (tid == 0) {
            float r2 = sre[256], i2 = sim[256];
            n_mag[obase + 256] = fmaxf(sqrtf(r2 * r2 + i2 * i2), 1e-6f);
        }
    }
}

// K2: rolling 10% quantile over 31-wide time window (edge-replicated)
//     = 4th-smallest of 31. grid (2, NT, B), 256 thr.
__global__ __launch_bounds__(256) void quant_kernel(const float* __restrict__ n_mag,
                                                    float* __restrict__ qf) {
    const int f = blockIdx.x * 256 + threadIdx.x;
    if (f >= NF) return;
    const int t = blockIdx.y, b = blockIdx.z;
    const float* __restrict__ p = n_mag + b * NT * NF + f;
    float m0 = 3.4e38f, m1 = 3.4e38f, m2 = 3.4e38f, m3 = 3.4e38f;
    #pragma unroll
    for (int dt = -15; dt <= 15; ++dt) {
        int tt = t + dt;
        tt = tt < 0 ? 0 : (tt > NT - 1 ? NT - 1 : tt);
        const float v = p[tt * NF];
        // branchless bubble-insert into 4 smallest
        const float a0 = fminf(m0, v);  const float c0 = fmaxf(m0, v);
        const float a1 = fminf(m1, c0); const float c1 = fmaxf(m1, c0);
        const float a2 = fminf(m2, c1); const float c2 = fmaxf(m2, c1);
        const float a3 = fminf(m3, c2);
        m0 = a0; m1 = a1; m2 = a2; m3 = a3;
    }
    qf[(b * NT + t) * NF + f] = m3;
}

// K3: avg pool k=5 along freq, zero-padded, count_include_pad
__global__ __launch_bounds__(256) void fpool_kernel(const float* __restrict__ qf,
                                                    float* __restrict__ pooled) {
    const int f = blockIdx.x * 256 + threadIdx.x;
    if (f >= NF) return;
    const int t = blockIdx.y, b = blockIdx.z;
    const float* __restrict__ row = qf + (b * NT + t) * NF;
    float acc = 0.0f;
    #pragma unroll
    for (int df = -2; df <= 2; ++df) {
        const int ff = f + df;
        if (ff >= 0 && ff < NF) acc += row[ff];
    }
    pooled[(b * NT + t) * NF + f] = acc * (1.0f / 5.0f);
}

// K4: avg pool k=9 along time (zero-pad) + floor clamp + sigmoid mask + apply to e_spec in place
__global__ __launch_bounds__(256) void mask_kernel(const float* __restrict__ pooled,
                                                   float2* __restrict__ e_spec) {
    const int f = blockIdx.x * 256 + threadIdx.x;
    if (f >= NF) return;
    const int t = blockIdx.y, b = blockIdx.z;
    float acc = 0.0f;
    #pragma unroll
    for (int dt = -4; dt <= 4; ++dt) {
        const int tt = t + dt;
        if (tt >= 0 && tt < NT) acc += pooled[(b * NT + tt) * NF + f];
    }
    const float fl = fmaxf(acc * (1.0f / 9.0f), 1e-6f);
    const int idx = (b * NT + t) * NF + f;
    const float2 e = e_spec[idx];
    const float a = sqrtf(e.x * e.x + e.y * e.y);
    const float emag = fmaxf(a, 1e-6f);
    const float xarg = (emag - 1.5f * fl) / (0.15f * fl + 1e-6f);
    const float mask = 1.0f / (1.0f + expf(-xarg));
    const float fm = 0.08f + 0.92f * (0.65f + 0.35f * mask);
    const float scale = emag * fm / fmaxf(a, 1e-12f);
    e_spec[idx] = make_float2(e.x * scale, e.y * scale);
}

// K5: ISTFT per frame: hermitian expand -> inverse FFT -> *window -> frames buffer
__global__ __launch_bounds__(256) void istft_kernel(const float2* __restrict__ g,
                                                    float* __restrict__ frames) {
    __shared__ float sre[512], sim[512], twc[256], tws[256];
    const int tid = threadIdx.x;
    const int t = blockIdx.x, b = blockIdx.y;

    const float ang = TWO_PI * (float)tid * (1.0f / 512.0f);
    twc[tid] = cosf(ang);
    tws[tid] = sinf(ang);

    const int ibase = (b * NT + t) * NF;
    const float2 v = g[ibase + tid];
    const int r0 = __brev((unsigned)tid) >> 23;
    sre[r0] = v.x; sim[r0] = v.y;
    if (tid == 0) {
        const float2 v2 = g[ibase + 256];
        const int r = __brev(256u) >> 23;
        sre[r] = v2.x; sim[r] = v2.y;
    } else {
        const int n = 512 - tid;
        const int r = __brev((unsigned)n) >> 23;
        sre[r] = v.x; sim[r] = -v.y;
    }
    __syncthreads();
    fft512(sre, sim, twc, tws, +1.0f, tid);

    const int obase = (b * NT + t) * NFFT;
    #pragma unroll
    for (int q = 0; q < 2; ++q) {
        const int n = tid + q * 256;
        const float w = 0.5f * (1.0f - cosf(TWO_PI * (float)n * (1.0f / 512.0f)));
        frames[obase + n] = sre[n] * (1.0f / 512.0f) * w;
    }
}

// K6: overlap-add gather + analytic window-square normalization + crop
__global__ __launch_bounds__(256) void ola_kernel(const float* __restrict__ frames,
                                                  float* __restrict__ out) {
    const int j = blockIdx.x * 256 + threadIdx.x;
    if (j >= BATCH * LEN) return;
    const int b = j / LEN;
    const int jj = j - b * LEN;
    const int i = jj + PADC;                 // index in padded signal coords
    int t_lo = (i >= 384) ? ((i - 384) >> 7) : 0;   // ceil((i-511)/128), clamped
    int t_hi = i >> 7; if (t_hi > NT - 1) t_hi = NT - 1;
    float acc = 0.0f, wacc = 0.0f;
    for (int t = t_lo; t <= t_hi; ++t) {
        const int n = i - (t << 7);
        const float w = 0.5f * (1.0f - cosf(TWO_PI * (float)n * (1.0f / 512.0f)));
        acc  += frames[(b * NT + t) * NFFT + n];
        wacc += w * w;
    }
    out[j] = acc / fmaxf(wacc, 1e-11f);
}

extern "C" void kernel_launch(void* const* d_in, const int* in_sizes, int n_in,
                              void* d_out, int out_size, void* d_ws, size_t ws_size,
                              hipStream_t stream) {
    const float* noisy    = (const float*)d_in[0];
    const float* enhanced = (const float*)d_in[1];
    float* out = (float*)d_out;

    // workspace layout (floats):
    //   e_spec : [0, 10288224)              (16*1251*257 float2)
    //   n_mag  : [10288224, 15432336)
    //   qf     : [15432336, 20576448)
    //   pooled : [20576448, 25720560)
    //   frames : reuses n_mag+qf region (needs 10248192 floats <= 10288224)
    float* ws = (float*)d_ws;
    float2* e_spec = (float2*)ws;
    float* n_mag  = ws + 10288224;
    float* qf     = ws + 15432336;
    float* pooled = ws + 20576448;
    float* frames = ws + 10288224;

    dim3 blk(256);
    stft_kernel<<<dim3(NT, BATCH, 2), blk, 0, stream>>>(enhanced, noisy, e_spec, n_mag);
    quant_kernel<<<dim3(2, NT, BATCH), blk, 0, stream>>>(n_mag, qf);
    fpool_kernel<<<dim3(2, NT, BATCH), blk, 0, stream>>>(qf, pooled);
    mask_kernel <<<dim3(2, NT, BATCH), blk, 0, stream>>>(pooled, e_spec);
    istft_kernel<<<dim3(NT, BATCH), blk, 0, stream>>>(e_spec, frames);
    ola_kernel  <<<dim3((BATCH * LEN + 255) / 256), blk, 0, stream>>>(frames, out);
}

// Round 2
// 240.177 us; speedup vs baseline: 1.9752x; 1.9752x over previous
//
#include <hip/hip_runtime.h>
#include <math.h>

#define BATCH 16
#define LEN   160000
#define NFFT  512
#define HOP   128
#define NT    1251      // 1 + (160000+512-512)/128
#define NF    257
#define PADC  256
#define TWO_PI 6.28318530717958647692f
// padded LDS index: +1 float per 32 -> breaks power-of-2 bank aliasing
#define P(i) ((i) + ((i) >> 5))

__device__ __forceinline__ int reflect_idx(int j) {
    j = j < 0 ? -j : j;
    j = j >= LEN ? 2*LEN - 2 - j : j;
    return j;
}

__device__ __forceinline__ float hann(int n) {
    return 0.5f - 0.5f * __cosf(TWO_PI * (float)n * (1.0f / 512.0f));
}

// In-LDS 512-pt complex radix-2 DIT FFT, 256 threads, padded indexing,
// twiddles via fast __sincosf (no LDS table -> no twiddle conflicts).
// Input bit-reversed, output natural. sign=-1 fwd, +1 inv (unscaled).
__device__ __forceinline__ void fft512p(float* sre, float* sim, float sign, int tid) {
    #pragma unroll
    for (int s = 1; s <= 9; ++s) {
        const int half = 1 << (s - 1);
        const int k  = tid & (half - 1);
        const int i0 = ((tid >> (s - 1)) << s) + k;
        const int i1 = i0 + half;
        float wr, wi;
        if (s == 1) { wr = 1.0f; wi = 0.0f; }
        else __sincosf(sign * (TWO_PI / (float)(1 << s)) * (float)k, &wi, &wr);
        const int p0 = P(i0), p1 = P(i1);
        const float ar = sre[p0], ai = sim[p0];
        const float br = sre[p1], bi = sim[p1];
        const float tr = br * wr - bi * wi;
        const float ti = br * wi + bi * wr;
        sre[p0] = ar + tr; sim[p0] = ai + ti;
        sre[p1] = ar - tr; sim[p1] = ai - ti;
        __syncthreads();
    }
}

// K1: STFT of BOTH signals via one complex FFT: z = enh + i*noi.
//     X(k) = (Z(k)+conj(Z(512-k)))/2 -> e_spec;  Y(k) = (Z(k)-conj(Z(512-k)))/2i -> n_mag.
__global__ __launch_bounds__(256) void stft_kernel(const float* __restrict__ enh,
                                                   const float* __restrict__ noi,
                                                   float2* __restrict__ e_spec,
                                                   float*  __restrict__ n_mag) {
    __shared__ float sre[528], sim[528];
    const int tid = threadIdx.x;
    const int t = blockIdx.x, b = blockIdx.y;

    const int base = t * HOP - PADC;
    #pragma unroll
    for (int q = 0; q < 2; ++q) {
        const int n = tid + q * 256;
        const int j = reflect_idx(base + n);
        const float w = hann(n);
        const int r = __brev((unsigned)n) >> 23;
        sre[P(r)] = enh[b * LEN + j] * w;
        sim[P(r)] = noi[b * LEN + j] * w;
    }
    __syncthreads();
    fft512p(sre, sim, -1.0f, tid);

    const int obase = (b * NT + t) * NF;
    for (int kk = tid; kk < NF; kk += 256) {
        const float zr = sre[P(kk)], zi = sim[P(kk)];
        const int n2 = (512 - kk) & 511;
        const float yr = sre[P(n2)], yi = sim[P(n2)];
        const float er = 0.5f * (zr + yr), ei = 0.5f * (zi - yi);
        const float nr = 0.5f * (zi + yi), ni = 0.5f * (yr - zr);
        e_spec[obase + kk] = make_float2(er, ei);
        n_mag[obase + kk] = fmaxf(sqrtf(nr * nr + ni * ni), 1e-6f);
    }
}

// K2: rolling 10% quantile over 31-wide time window (edge-replicated)
//     = 4th-smallest of 31. Flat index over B*NT*NF.
__global__ __launch_bounds__(256) void quant_kernel(const float* __restrict__ n_mag,
                                                    float* __restrict__ qf) {
    const int idx = blockIdx.x * 256 + threadIdx.x;
    if (idx >= BATCH * NT * NF) return;
    const int f  = idx % NF;
    const int bt = idx / NF;
    const int t  = bt % NT;
    const float* __restrict__ p = n_mag + (bt - t) * NF + f;  // base of batch b
    float m0 = 3.4e38f, m1 = 3.4e38f, m2 = 3.4e38f, m3 = 3.4e38f;
    #pragma unroll
    for (int dt = -15; dt <= 15; ++dt) {
        int tt = t + dt;
        tt = tt < 0 ? 0 : (tt > NT - 1 ? NT - 1 : tt);
        const float v = p[tt * NF];
        const float a0 = fminf(m0, v);  const float c0 = fmaxf(m0, v);
        const float a1 = fminf(m1, c0); const float c1 = fmaxf(m1, c0);
        const float a2 = fminf(m2, c1); const float c2 = fmaxf(m2, c1);
        const float a3 = fminf(m3, c2);
        m0 = a0; m1 = a1; m2 = a2; m3 = a3;
    }
    qf[idx] = m3;
}

// K3: avg pool k=5 along freq, zero-padded, count_include_pad. Flat index.
__global__ __launch_bounds__(256) void fpool_kernel(const float* __restrict__ qf,
                                                    float* __restrict__ pooled) {
    const int idx = blockIdx.x * 256 + threadIdx.x;
    if (idx >= BATCH * NT * NF) return;
    const int f  = idx % NF;
    const int bt = idx / NF;
    const float* __restrict__ row = qf + bt * NF;
    float acc = 0.0f;
    #pragma unroll
    for (int df = -2; df <= 2; ++df) {
        const int ff = f + df;
        if (ff >= 0 && ff < NF) acc += row[ff];
    }
    pooled[idx] = acc * (1.0f / 5.0f);
}

// K4: fused [time-pool k=9 + floor + sigmoid mask + apply] + ISTFT of TWO
//     frames via one complex IFFT: C = G1full + i*G2full, x1=Re(c), x2=Im(c).
__global__ __launch_bounds__(256) void istft_kernel(const float2* __restrict__ g,
                                                    const float* __restrict__ pooled,
                                                    float* __restrict__ frames) {
    __shared__ float sre[528], sim[528];
    __shared__ float gr[2][NF], gi[2][NF];
    const int tid = threadIdx.x;
    const int t0 = 2 * blockIdx.x, b = blockIdx.y;

    #pragma unroll
    for (int h = 0; h < 2; ++h) {
        const int t = t0 + h;
        const bool valid = (t < NT);
        for (int kk = tid; kk < NF; kk += 256) {
            float grv = 0.0f, giv = 0.0f;
            if (valid) {
                // time avg-pool k=9, zero-padded
                const float* __restrict__ pc = pooled + b * NT * NF + kk;
                float acc = 0.0f;
                #pragma unroll
                for (int dt = -4; dt <= 4; ++dt) {
                    const int tt = t + dt;
                    if (tt >= 0 && tt < NT) acc += pc[tt * NF];
                }
                const float fl = fmaxf(acc * (1.0f / 9.0f), 1e-6f);
                const float2 e = g[(b * NT + t) * NF + kk];
                const float a = sqrtf(e.x * e.x + e.y * e.y);
                const float emag = fmaxf(a, 1e-6f);
                const float xarg = (emag - 1.5f * fl) / (0.15f * fl + 1e-6f);
                const float mask = 1.0f / (1.0f + __expf(-xarg));
                const float fm = 0.08f + 0.92f * (0.65f + 0.35f * mask);
                const float scale = emag * fm / fmaxf(a, 1e-12f);
                grv = e.x * scale; giv = e.y * scale;
            }
            gr[h][kk] = grv; gi[h][kk] = giv;
        }
    }
    __syncthreads();

    // build C(n) = G1full(n) + i*G2full(n), scatter bit-reversed
    #pragma unroll
    for (int q = 0; q < 2; ++q) {
        const int n = tid + q * 256;
        float cr, ci;
        if (n <= 256) {
            cr = gr[0][n] - gi[1][n];
            ci = gi[0][n] + gr[1][n];
        } else {
            const int m = 512 - n;
            cr = gr[0][m] + gi[1][m];
            ci = gr[1][m] - gi[0][m];
        }
        const int r = __brev((unsigned)n) >> 23;
        sre[P(r)] = cr; sim[P(r)] = ci;
    }
    __syncthreads();
    fft512p(sre, sim, +1.0f, tid);

    const int ob0 = (b * NT + t0) * NFFT;
    const bool has1 = (t0 + 1 < NT);
    #pragma unroll
    for (int q = 0; q < 2; ++q) {
        const int n = tid + q * 256;
        const float w = hann(n) * (1.0f / 512.0f);
        frames[ob0 + n] = sre[P(n)] * w;
        if (has1) frames[ob0 + NFFT + n] = sim[P(n)] * w;
    }
}

// K5: overlap-add gather + analytic window-square normalization + crop
__global__ __launch_bounds__(256) void ola_kernel(const float* __restrict__ frames,
                                                  float* __restrict__ out) {
    const int j = blockIdx.x * 256 + threadIdx.x;
    if (j >= BATCH * LEN) return;
    const int b = j / LEN;
    const int jj = j - b * LEN;
    const int i = jj + PADC;
    int t_lo = (i >= 384) ? ((i - 384) >> 7) : 0;
    int t_hi = i >> 7; if (t_hi > NT - 1) t_hi = NT - 1;
    float acc = 0.0f, wacc = 0.0f;
    for (int t = t_lo; t <= t_hi; ++t) {
        const int n = i - (t << 7);
        const float w = hann(n);
        acc  += frames[(b * NT + t) * NFFT + n];
        wacc += w * w;
    }
    out[j] = acc / fmaxf(wacc, 1e-11f);
}

extern "C" void kernel_launch(void* const* d_in, const int* in_sizes, int n_in,
                              void* d_out, int out_size, void* d_ws, size_t ws_size,
                              hipStream_t stream) {
    const float* noisy    = (const float*)d_in[0];
    const float* enhanced = (const float*)d_in[1];
    float* out = (float*)d_out;

    // workspace layout (floats):
    //   e_spec : [0, 10288224)              (16*1251*257 float2)
    //   n_mag  : [10288224, 15432336)
    //   qf     : [15432336, 20576448)
    //   pooled : [20576448, 25720560)
    //   frames : reuses n_mag+qf region (10248192 floats <= 10288224)
    float* ws = (float*)d_ws;
    float2* e_spec = (float2*)ws;
    float* n_mag  = ws + 10288224;
    float* qf     = ws + 15432336;
    float* pooled = ws + 20576448;
    float* frames = ws + 10288224;

    dim3 blk(256);
    const int nelem = BATCH * NT * NF;
    stft_kernel<<<dim3(NT, BATCH), blk, 0, stream>>>(enhanced, noisy, e_spec, n_mag);
    quant_kernel<<<dim3((nelem + 255) / 256), blk, 0, stream>>>(n_mag, qf);
    fpool_kernel<<<dim3((nelem + 255) / 256), blk, 0, stream>>>(qf, pooled);
    istft_kernel<<<dim3((NT + 1) / 2, BATCH), blk, 0, stream>>>(e_spec, pooled, frames);
    ola_kernel  <<<dim3((BATCH * LEN + 255) / 256), blk, 0, stream>>>(frames, out);
}

// Round 3
// 232.149 us; speedup vs baseline: 2.0436x; 1.0346x over previous
//
#include <hip/hip_runtime.h>
#include <math.h>

#define BATCH 16
#define LEN   160000
#define NFFT  512
#define HOP   128
#define NT    1251      // 1 + (160000+512-512)/128
#define NF    257
#define PADC  256
#define TWO_PI 6.28318530717958647692f
// padded LDS index: +1 float per 32 -> breaks power-of-2 bank aliasing
#define P(i) ((i) + ((i) >> 5))

__device__ __forceinline__ int reflect_idx(int j) {
    j = j < 0 ? -j : j;
    j = j >= LEN ? 2*LEN - 2 - j : j;
    return j;
}

__device__ __forceinline__ float hann(int n) {
    return 0.5f - 0.5f * __cosf(TWO_PI * (float)n * (1.0f / 512.0f));
}

// Stage-major twiddle table: stage s (1..9) has 2^(s-1) entries at offset
// 2^(s-1)-1; entry k holds cos/sin(2*pi*k/2^s). 511 entries per table.
// Wave reads at stage s are same-address broadcast (s<=6) or stride-1
// (s>=7) -> conflict-free, unlike a bit-indexed 256-entry table.
__device__ __forceinline__ void init_tw(float* twc, float* tws, int tid) {
    for (int i = tid; i < 511; i += 256) {
        const int s = 32 - __clz(i + 1);
        const int k = (i + 1) - (1 << (s - 1));
        float sn, cs;
        __sincosf(TWO_PI * (float)k / (float)(1 << s), &sn, &cs);
        twc[i] = cs; tws[i] = sn;
    }
}

// In-LDS 512-pt complex radix-2 DIT FFT, 256 threads, padded indexing.
// Input bit-reversed, output natural. sign=-1 fwd, +1 inv (unscaled).
__device__ __forceinline__ void fft512p(float* sre, float* sim,
                                        const float* twc, const float* tws,
                                        float sign, int tid) {
    #pragma unroll
    for (int s = 1; s <= 9; ++s) {
        const int half = 1 << (s - 1);
        const int k  = tid & (half - 1);
        const int i0 = ((tid >> (s - 1)) << s) + k;
        const int i1 = i0 + half;
        const int w  = (half - 1) + k;
        const float wr = twc[w];
        const float wi = sign * tws[w];
        const int p0 = P(i0), p1 = P(i1);
        const float ar = sre[p0], ai = sim[p0];
        const float br = sre[p1], bi = sim[p1];
        const float tr = br * wr - bi * wi;
        const float ti = br * wi + bi * wr;
        sre[p0] = ar + tr; sim[p0] = ai + ti;
        sre[p1] = ar - tr; sim[p1] = ai - ti;
        __syncthreads();
    }
}

// K1: STFT of BOTH signals via one complex FFT: z = enh + i*noi.
__global__ __launch_bounds__(256) void stft_kernel(const float* __restrict__ enh,
                                                   const float* __restrict__ noi,
                                                   float2* __restrict__ e_spec,
                                                   float*  __restrict__ n_mag) {
    __shared__ float sre[528], sim[528], twc[511], tws[511];
    const int tid = threadIdx.x;
    const int t = blockIdx.x, b = blockIdx.y;

    init_tw(twc, tws, tid);

    const int base = t * HOP - PADC;
    #pragma unroll
    for (int q = 0; q < 2; ++q) {
        const int n = tid + q * 256;
        const int j = reflect_idx(base + n);
        const float w = hann(n);
        const int r = __brev((unsigned)n) >> 23;
        sre[P(r)] = enh[b * LEN + j] * w;
        sim[P(r)] = noi[b * LEN + j] * w;
    }
    __syncthreads();
    fft512p(sre, sim, twc, tws, -1.0f, tid);

    const int obase = (b * NT + t) * NF;
    for (int kk = tid; kk < NF; kk += 256) {
        const float zr = sre[P(kk)], zi = sim[P(kk)];
        const int n2 = (512 - kk) & 511;
        const float yr = sre[P(n2)], yi = sim[P(n2)];
        const float er = 0.5f * (zr + yr), ei = 0.5f * (zi - yi);
        const float nr = 0.5f * (zi + yi), ni = 0.5f * (yr - zr);
        e_spec[obase + kk] = make_float2(er, ei);
        n_mag[obase + kk] = fmaxf(sqrtf(nr * nr + ni * ni), 1e-6f);
    }
}

// K2: fused rolling-quantile (4th-smallest of 31 along t, edge-replicated)
//     + freq avg-pool k=5 (zero-pad) via LDS. Block = one (b,t) row.
__global__ __launch_bounds__(256) void quantpool_kernel(const float* __restrict__ n_mag,
                                                        float* __restrict__ pooled) {
    __shared__ float q[NF];
    const int tid = threadIdx.x;
    const int t = blockIdx.x, b = blockIdx.y;
    const float* __restrict__ pb = n_mag + b * NT * NF;

    for (int f = tid; f < NF; f += 256) {
        float m0 = 3.4e38f, m1 = 3.4e38f, m2 = 3.4e38f, m3 = 3.4e38f;
        #pragma unroll
        for (int dt = -15; dt <= 15; ++dt) {
            int tt = t + dt;
            tt = tt < 0 ? 0 : (tt > NT - 1 ? NT - 1 : tt);
            const float v = pb[tt * NF + f];
            const float a0 = fminf(m0, v);  const float c0 = fmaxf(m0, v);
            const float a1 = fminf(m1, c0); const float c1 = fmaxf(m1, c0);
            const float a2 = fminf(m2, c1); const float c2 = fmaxf(m2, c1);
            const float a3 = fminf(m3, c2);
            m0 = a0; m1 = a1; m2 = a2; m3 = a3;
        }
        q[f] = m3;
    }
    __syncthreads();

    for (int f = tid; f < NF; f += 256) {
        float acc = 0.0f;
        #pragma unroll
        for (int df = -2; df <= 2; ++df) {
            const int ff = f + df;
            if (ff >= 0 && ff < NF) acc += q[ff];
        }
        pooled[(b * NT + t) * NF + f] = acc * (1.0f / 5.0f);
    }
}

// K3: fused [time-pool k=9 + floor + sigmoid mask + apply] + ISTFT of TWO
//     frames via one complex IFFT: C = G1full + i*G2full.
__global__ __launch_bounds__(256) void istft_kernel(const float2* __restrict__ g,
                                                    const float* __restrict__ pooled,
                                                    float* __restrict__ frames) {
    __shared__ float sre[528], sim[528], twc[511], tws[511];
    __shared__ float gr[2][NF], gi[2][NF];
    const int tid = threadIdx.x;
    const int t0 = 2 * blockIdx.x, b = blockIdx.y;

    init_tw(twc, tws, tid);

    #pragma unroll
    for (int h = 0; h < 2; ++h) {
        const int t = t0 + h;
        const bool valid = (t < NT);
        for (int kk = tid; kk < NF; kk += 256) {
            float grv = 0.0f, giv = 0.0f;
            if (valid) {
                const float* __restrict__ pc = pooled + b * NT * NF + kk;
                float acc = 0.0f;
                #pragma unroll
                for (int dt = -4; dt <= 4; ++dt) {
                    const int tt = t + dt;
                    if (tt >= 0 && tt < NT) acc += pc[tt * NF];
                }
                const float fl = fmaxf(acc * (1.0f / 9.0f), 1e-6f);
                const float2 e = g[(b * NT + t) * NF + kk];
                const float a = sqrtf(e.x * e.x + e.y * e.y);
                const float emag = fmaxf(a, 1e-6f);
                const float xarg = (emag - 1.5f * fl) / (0.15f * fl + 1e-6f);
                const float mask = 1.0f / (1.0f + __expf(-xarg));
                const float fm = 0.08f + 0.92f * (0.65f + 0.35f * mask);
                const float scale = emag * fm / fmaxf(a, 1e-12f);
                grv = e.x * scale; giv = e.y * scale;
            }
            gr[h][kk] = grv; gi[h][kk] = giv;
        }
    }
    __syncthreads();

    #pragma unroll
    for (int q = 0; q < 2; ++q) {
        const int n = tid + q * 256;
        float cr, ci;
        if (n <= 256) {
            cr = gr[0][n] - gi[1][n];
            ci = gi[0][n] + gr[1][n];
        } else {
            const int m = 512 - n;
            cr = gr[0][m] + gi[1][m];
            ci = gr[1][m] - gi[0][m];
        }
        const int r = __brev((unsigned)n) >> 23;
        sre[P(r)] = cr; sim[P(r)] = ci;
    }
    __syncthreads();
    fft512p(sre, sim, twc, tws, +1.0f, tid);

    const int ob0 = (b * NT + t0) * NFFT;
    const bool has1 = (t0 + 1 < NT);
    #pragma unroll
    for (int q = 0; q < 2; ++q) {
        const int n = tid + q * 256;
        const float w = hann(n) * (1.0f / 512.0f);
        frames[ob0 + n] = sre[P(n)] * w;
        if (has1) frames[ob0 + NFFT + n] = sim[P(n)] * w;
    }
}

// K4: overlap-add gather + window-square normalization + crop.
// Interior (4 overlapping frames): sum(hann^2 at hop 128) == 1.5 exactly.
__global__ __launch_bounds__(256) void ola_kernel(const float* __restrict__ frames,
                                                  float* __restrict__ out) {
    const int j = blockIdx.x * 256 + threadIdx.x;
    if (j >= BATCH * LEN) return;
    const int b = j / LEN;
    const int jj = j - b * LEN;
    const int i = jj + PADC;
    int t_lo = (i >= 384) ? ((i - 384) >> 7) : 0;
    int t_hi = i >> 7; if (t_hi > NT - 1) t_hi = NT - 1;
    if (t_hi - t_lo == 3) {
        const float* __restrict__ fp = frames + (b * NT + t_lo) * NFFT + (i - (t_lo << 7));
        // consecutive taps step 512 - 128 = 384 floats
        const float acc = fp[0] + fp[384] + fp[768] + fp[1152];
        out[j] = acc * (2.0f / 3.0f);
    } else {
        float acc = 0.0f, wacc = 0.0f;
        for (int t = t_lo; t <= t_hi; ++t) {
            const int n = i - (t << 7);
            const float w = hann(n);
            acc  += frames[(b * NT + t) * NFFT + n];
            wacc += w * w;
        }
        out[j] = acc / fmaxf(wacc, 1e-11f);
    }
}

extern "C" void kernel_launch(void* const* d_in, const int* in_sizes, int n_in,
                              void* d_out, int out_size, void* d_ws, size_t ws_size,
                              hipStream_t stream) {
    const float* noisy    = (const float*)d_in[0];
    const float* enhanced = (const float*)d_in[1];
    float* out = (float*)d_out;

    // workspace layout (floats), total 25680528 (~102.7 MB):
    //   e_spec : [0, 10288224)              (16*1251*257 float2)
    //   pooled : [10288224, 15432336)
    //   n_mag  : [15432336, 20576448)       (dead after quantpool)
    //   frames : [15432336, 25680528)       (reuses dead n_mag region)
    float* ws = (float*)d_ws;
    float2* e_spec = (float2*)ws;
    float* pooled = ws + 10288224;
    float* n_mag  = ws + 15432336;
    float* frames = ws + 15432336;

    dim3 blk(256);
    stft_kernel     <<<dim3(NT, BATCH), blk, 0, stream>>>(enhanced, noisy, e_spec, n_mag);
    quantpool_kernel<<<dim3(NT, BATCH), blk, 0, stream>>>(n_mag, pooled);
    istft_kernel    <<<dim3((NT + 1) / 2, BATCH), blk, 0, stream>>>(e_spec, pooled, frames);
    ola_kernel      <<<dim3((BATCH * LEN + 255) / 256), blk, 0, stream>>>(frames, out);
}

// Round 4
// 230.578 us; speedup vs baseline: 2.0575x; 1.0068x over previous
//
#include <hip/hip_runtime.h>
#include <math.h>

#define BATCH 16
#define LEN   160000
#define NFFT  512
#define HOP   128
#define NT    1251      // 1 + (160000+512-512)/128
#define NF    257
#define PADC  256
#define TWO_PI 6.28318530717958647692f
// padded LDS index: +1 float per 32 -> breaks power-of-2 bank aliasing
#define P(i) ((i) + ((i) >> 5))
#define FBUF 528        // padded 512-float FFT region (P(511)=526 < 528)
#define GSTR 264        // staging row stride: 2 rows == FBUF exactly

__device__ __forceinline__ int reflect_idx(int j) {
    j = j < 0 ? -j : j;
    j = j >= LEN ? 2*LEN - 2 - j : j;
    return j;
}

__device__ __forceinline__ float hann(int n) {
    return 0.5f - 0.5f * __cosf(TWO_PI * (float)n * (1.0f / 512.0f));
}

// 8-point DFT in registers. y[m] = sum_r v[r] * exp(sign*2*pi*i*r*m/8).
__device__ __forceinline__ void dft8(float vr[8], float vi[8], float sign) {
    const float K = 0.70710678118654752f;
    float ar=vr[0]+vr[4], ai=vi[0]+vi[4];
    float br=vr[0]-vr[4], bi=vi[0]-vi[4];
    float cr=vr[2]+vr[6], ci=vi[2]+vi[6];
    float dr=vr[2]-vr[6], di=vi[2]-vi[6];
    float er=vr[1]+vr[5], ei=vi[1]+vi[5];
    float fr=vr[1]-vr[5], fi=vi[1]-vi[5];
    float gr=vr[3]+vr[7], gi=vi[3]+vi[7];
    float hr=vr[3]-vr[7], hi=vi[3]-vi[7];
    const float W4dr = -sign*di, W4di = sign*dr;
    const float W4hr = -sign*hi, W4hi = sign*hr;
    const float E0r=ar+cr, E0i=ai+ci, E2r=ar-cr, E2i=ai-ci;
    const float E1r=br+W4dr, E1i=bi+W4di, E3r=br-W4dr, E3i=bi-W4di;
    const float O0r=er+gr, O0i=ei+gi, O2r=er-gr, O2i=ei-gi;
    const float O1r=fr+W4hr, O1i=fi+W4hi, O3r=fr-W4hr, O3i=fi-W4hi;
    const float T1r = K*(O1r - sign*O1i), T1i = K*(O1i + sign*O1r);
    const float T2r = -sign*O2i,          T2i = sign*O2r;
    const float T3r = K*(-O3r - sign*O3i), T3i = K*(-O3i + sign*O3r);
    vr[0]=E0r+O0r; vi[0]=E0i+O0i;  vr[4]=E0r-O0r; vi[4]=E0i-O0i;
    vr[1]=E1r+T1r; vi[1]=E1i+T1i;  vr[5]=E1r-T1r; vi[5]=E1i-T1i;
    vr[2]=E2r+T2r; vi[2]=E2i+T2i;  vr[6]=E2r-T2r; vi[6]=E2i-T2i;
    vr[3]=E3r+T3r; vi[3]=E3i+T3i;  vr[7]=E3r-T3r; vi[7]=E3i-T3i;
}

// One Stockham radix-8 pass (one wave = one FFT, j in 0..63).
// Reads sR/sI at j+64r, twiddles by exp(sign*2pi*i*(j%NS)*r/(8*NS)),
// dft8, writes dR/dI at (j/NS)*8*NS + j%NS + r*NS. All padded via P().
template<int NS>
__device__ __forceinline__ void fft_pass(const float* sR, const float* sI,
                                         float* dR, float* dI, int j, float sign) {
    float vr[8], vi[8];
    #pragma unroll
    for (int r = 0; r < 8; ++r) { vr[r] = sR[P(j + 64*r)]; vi[r] = sI[P(j + 64*r)]; }
    const float th = sign * (TWO_PI / (8.0f * (float)NS)) * (float)(j & (NS - 1));
    float w1r, w1i; __sincosf(th, &w1i, &w1r);
    float wr = w1r, wi = w1i;
    #pragma unroll
    for (int r = 1; r < 8; ++r) {
        const float tr = vr[r]*wr - vi[r]*wi;
        vi[r] = vr[r]*wi + vi[r]*wr; vr[r] = tr;
        const float nwr = wr*w1r - wi*w1i;
        wi = wr*w1i + wi*w1r; wr = nwr;
    }
    dft8(vr, vi, sign);
    const int base = ((j / NS) * (8 * NS)) + (j & (NS - 1));
    #pragma unroll
    for (int r = 0; r < 8; ++r) { dR[P(base + r*NS)] = vr[r]; dI[P(base + r*NS)] = vi[r]; }
}

// K1: STFT of BOTH signals via one complex FFT per frame: z = enh + i*noi.
// 4 frames per block (one per wave), radix-8 Stockham, pass0 reads global.
__global__ __launch_bounds__(256) void stft_kernel(const float* __restrict__ enh,
                                                   const float* __restrict__ noi,
                                                   float2* __restrict__ e_spec,
                                                   float*  __restrict__ n_mag) {
    __shared__ float Ar[4*FBUF], Ai[4*FBUF], Br[4*FBUF], Bi[4*FBUF];
    const int tid = threadIdx.x;
    const int w = tid >> 6, j = tid & 63;
    const int tr_ = blockIdx.x * 4 + w;
    const bool live = tr_ < NT;
    const int t = live ? tr_ : NT - 1;
    const int b = blockIdx.y;
    float* ar = Ar + w*FBUF; float* ai = Ai + w*FBUF;
    float* br = Br + w*FBUF; float* bi = Bi + w*FBUF;

    // pass 0: global -> registers (windowed, reflect-padded), dft8, write A
    {
        const int sbase = t * HOP - PADC;
        const float* __restrict__ pe = enh + b * LEN;
        const float* __restrict__ pn = noi + b * LEN;
        float vr[8], vi[8];
        #pragma unroll
        for (int r = 0; r < 8; ++r) {
            const int n = j + 64*r;
            const int idx = reflect_idx(sbase + n);
            const float wd = hann(n);
            vr[r] = pe[idx] * wd;
            vi[r] = pn[idx] * wd;
        }
        dft8(vr, vi, -1.0f);
        #pragma unroll
        for (int r = 0; r < 8; ++r) { ar[P(8*j + r)] = vr[r]; ai[P(8*j + r)] = vi[r]; }
    }
    __syncthreads();
    fft_pass<8> (ar, ai, br, bi, j, -1.0f);
    __syncthreads();
    fft_pass<64>(br, bi, ar, ai, j, -1.0f);
    __syncthreads();

    // extract rfft of both signals: X=(Z(k)+conj(Z(512-k)))/2, Y=(Z(k)-conj(Z(512-k)))/2i
    if (live) {
        const int obase = (b * NT + t) * NF;
        #pragma unroll
        for (int r = 0; r < 5; ++r) {
            const int kk = j + 64*r;
            if (kk > 256) break;
            if (r == 4 && j != 0) break;
            const float zr = ar[P(kk)], zi = ai[P(kk)];
            const int n2 = (512 - kk) & 511;
            const float yr = ar[P(n2)], yi = ai[P(n2)];
            const float er = 0.5f*(zr + yr), ei = 0.5f*(zi - yi);
            const float nr = 0.5f*(zi + yi), ni = 0.5f*(yr - zr);
            e_spec[obase + kk] = make_float2(er, ei);
            n_mag[obase + kk] = fmaxf(sqrtf(nr*nr + ni*ni), 1e-6f);
        }
    }
}

// K2: fused rolling-quantile (4th-smallest of 31 along t, edge-replicated)
//     + freq avg-pool k=5 (zero-pad) via LDS. Block = one (b,t) row.
__global__ __launch_bounds__(256) void quantpool_kernel(const float* __restrict__ n_mag,
                                                        float* __restrict__ pooled) {
    __shared__ float q[NF];
    const int tid = threadIdx.x;
    const int t = blockIdx.x, b = blockIdx.y;
    const float* __restrict__ pb = n_mag + b * NT * NF;

    for (int f = tid; f < NF; f += 256) {
        float m0 = 3.4e38f, m1 = 3.4e38f, m2 = 3.4e38f, m3 = 3.4e38f;
        #pragma unroll
        for (int dt = -15; dt <= 15; ++dt) {
            int tt = t + dt;
            tt = tt < 0 ? 0 : (tt > NT - 1 ? NT - 1 : tt);
            const float v = pb[tt * NF + f];
            const float a0 = fminf(m0, v);  const float c0 = fmaxf(m0, v);
            const float a1 = fminf(m1, c0); const float c1 = fmaxf(m1, c0);
            const float a2 = fminf(m2, c1); const float c2 = fmaxf(m2, c1);
            const float a3 = fminf(m3, c2);
            m0 = a0; m1 = a1; m2 = a2; m3 = a3;
        }
        q[f] = m3;
    }
    __syncthreads();

    for (int f = tid; f < NF; f += 256) {
        float acc = 0.0f;
        #pragma unroll
        for (int df = -2; df <= 2; ++df) {
            const int ff = f + df;
            if (ff >= 0 && ff < NF) acc += q[ff];
        }
        pooled[(b * NT + t) * NF + f] = acc * (1.0f / 5.0f);
    }
}

// K3: fused [time-pool k=9 + floor + sigmoid mask + apply] + ISTFT.
// 8 frames per block: 4 packed IFFTs (one per wave), radix-8 Stockham.
// Staging gr/gi (8 rows x 264) is reused as the 2nd FFT buffer after pass0.
__global__ __launch_bounds__(256) void istft_kernel(const float2* __restrict__ g,
                                                    const float* __restrict__ pooled,
                                                    float* __restrict__ frames) {
    __shared__ float gr[8*GSTR], gi[8*GSTR];   // 2112 floats = 4*FBUF each
    __shared__ float Ar[4*FBUF], Ai[4*FBUF];
    const int tid = threadIdx.x;
    const int w = tid >> 6, j = tid & 63;
    const int t0 = blockIdx.x * 8, b = blockIdx.y;

    // mask phase: fill gr/gi for 8 frames (zeros for out-of-range frames)
    for (int e = tid; e < 8 * NF; e += 256) {
        const int h = e / NF;
        const int kk = e - h * NF;
        const int t = t0 + h;
        float grv = 0.0f, giv = 0.0f;
        if (t < NT) {
            const float* __restrict__ pc = pooled + b * NT * NF + kk;
            float acc = 0.0f;
            #pragma unroll
            for (int dt = -4; dt <= 4; ++dt) {
                const int tt = t + dt;
                if (tt >= 0 && tt < NT) acc += pc[tt * NF];
            }
            const float fl = fmaxf(acc * (1.0f / 9.0f), 1e-6f);
            const float2 e2 = g[(b * NT + t) * NF + kk];
            const float a = sqrtf(e2.x * e2.x + e2.y * e2.y);
            const float emag = fmaxf(a, 1e-6f);
            const float xarg = (emag - 1.5f * fl) / (0.15f * fl + 1e-6f);
            const float mask = 1.0f / (1.0f + __expf(-xarg));
            const float fm = 0.08f + 0.92f * (0.65f + 0.35f * mask);
            const float scale = emag * fm / fmaxf(a, 1e-12f);
            grv = e2.x * scale; giv = e2.y * scale;
        }
        gr[h * GSTR + kk] = grv; gi[h * GSTR + kk] = giv;
    }
    __syncthreads();

    float* ar = Ar + w*FBUF; float* ai = Ai + w*FBUF;
    float* brB = gr + w*FBUF; float* biB = gi + w*FBUF;  // aliases own staging rows 2w,2w+1

    // pass 0: build packed C(n) = G1full + i*G2full from staging, dft8, write A
    {
        const float* g0r = gr + (2*w) * GSTR;
        const float* g0i = gi + (2*w) * GSTR;
        const float* g1r = gr + (2*w + 1) * GSTR;
        const float* g1i = gi + (2*w + 1) * GSTR;
        float vr[8], vi[8];
        #pragma unroll
        for (int r = 0; r < 8; ++r) {
            const int n = j + 64*r;
            float cr, ci;
            if (n <= 256) {
                cr = g0r[n] - g1i[n];
                ci = g0i[n] + g1r[n];
            } else {
                const int m = 512 - n;
                cr = g0r[m] + g1i[m];
                ci = g1r[m] - g0i[m];
            }
            vr[r] = cr; vi[r] = ci;
        }
        dft8(vr, vi, 1.0f);
        #pragma unroll
        for (int r = 0; r < 8; ++r) { ar[P(8*j + r)] = vr[r]; ai[P(8*j + r)] = vi[r]; }
    }
    __syncthreads();
    fft_pass<8> (ar, ai, brB, biB, j, 1.0f);   // staging rows 2w,2w+1 dead after pass0
    __syncthreads();
    fft_pass<64>(brB, biB, ar, ai, j, 1.0f);
    __syncthreads();

    // x1(n) = Re -> frame t0+2w, x2(n) = Im -> frame t0+2w+1
    const int ta = t0 + 2*w, tb = ta + 1;
    const float* fra = ar; const float* fia = ai;
    #pragma unroll
    for (int r = 0; r < 8; ++r) {
        const int n = j + 64*r;
        const float wd = hann(n) * (1.0f / 512.0f);
        if (ta < NT) frames[(b * NT + ta) * NFFT + n] = fra[P(n)] * wd;
        if (tb < NT) frames[(b * NT + tb) * NFFT + n] = fia[P(n)] * wd;
    }
}

// K4: overlap-add gather + window-square normalization + crop.
// Interior (4 overlapping frames): sum(hann^2 at hop 128) == 1.5 exactly.
__global__ __launch_bounds__(256) void ola_kernel(const float* __restrict__ frames,
                                                  float* __restrict__ out) {
    const int j = blockIdx.x * 256 + threadIdx.x;
    if (j >= BATCH * LEN) return;
    const int b = j / LEN;
    const int jj = j - b * LEN;
    const int i = jj + PADC;
    int t_lo = (i >= 384) ? ((i - 384) >> 7) : 0;
    int t_hi = i >> 7; if (t_hi > NT - 1) t_hi = NT - 1;
    if (t_hi - t_lo == 3) {
        const float* __restrict__ fp = frames + (b * NT + t_lo) * NFFT + (i - (t_lo << 7));
        const float acc = fp[0] + fp[384] + fp[768] + fp[1152];
        out[j] = acc * (2.0f / 3.0f);
    } else {
        float acc = 0.0f, wacc = 0.0f;
        for (int t = t_lo; t <= t_hi; ++t) {
            const int n = i - (t << 7);
            const float w = hann(n);
            acc  += frames[(b * NT + t) * NFFT + n];
            wacc += w * w;
        }
        out[j] = acc / fmaxf(wacc, 1e-11f);
    }
}

extern "C" void kernel_launch(void* const* d_in, const int* in_sizes, int n_in,
                              void* d_out, int out_size, void* d_ws, size_t ws_size,
                              hipStream_t stream) {
    const float* noisy    = (const float*)d_in[0];
    const float* enhanced = (const float*)d_in[1];
    float* out = (float*)d_out;

    // workspace layout (floats), total 25680528 (~102.7 MB):
    //   e_spec : [0, 10288224)              (16*1251*257 float2)
    //   pooled : [10288224, 15432336)
    //   n_mag  : [15432336, 20576448)       (dead after quantpool)
    //   frames : [15432336, 25680528)       (reuses dead n_mag region)
    float* ws = (float*)d_ws;
    float2* e_spec = (float2*)ws;
    float* pooled = ws + 10288224;
    float* n_mag  = ws + 15432336;
    float* frames = ws + 15432336;

    dim3 blk(256);
    stft_kernel     <<<dim3((NT + 3) / 4, BATCH), blk, 0, stream>>>(enhanced, noisy, e_spec, n_mag);
    quantpool_kernel<<<dim3(NT, BATCH), blk, 0, stream>>>(n_mag, pooled);
    istft_kernel    <<<dim3((NT + 7) / 8, BATCH), blk, 0, stream>>>(e_spec, pooled, frames);
    ola_kernel      <<<dim3((BATCH * LEN + 255) / 256), blk, 0, stream>>>(frames, out);
}

// Round 5
// 212.270 us; speedup vs baseline: 2.2349x; 1.0862x over previous
//
#include <hip/hip_runtime.h>
#include <math.h>

#define BATCH 16
#define LEN   160000
#define NFFT  512
#define HOP   128
#define NT    1251      // 1 + (160000+512-512)/128
#define NF    257
#define PADC  256
#define TWO_PI 6.28318530717958647692f
// padded LDS index: +1 float per 32 -> breaks power-of-2 bank aliasing
#define P(i) ((i) + ((i) >> 5))
#define FBUF 528        // padded 512-float FFT region (P(511)=526 < 528)
#define GSTR 264        // staging row stride: 2 rows == FBUF exactly

__device__ __forceinline__ int reflect_idx(int j) {
    j = j < 0 ? -j : j;
    j = j >= LEN ? 2*LEN - 2 - j : j;
    return j;
}

__device__ __forceinline__ float hann(int n) {
    return 0.5f - 0.5f * __cosf(TWO_PI * (float)n * (1.0f / 512.0f));
}

// 8-point DFT in registers. y[m] = sum_r v[r] * exp(sign*2*pi*i*r*m/8).
__device__ __forceinline__ void dft8(float vr[8], float vi[8], float sign) {
    const float K = 0.70710678118654752f;
    float ar=vr[0]+vr[4], ai=vi[0]+vi[4];
    float br=vr[0]-vr[4], bi=vi[0]-vi[4];
    float cr=vr[2]+vr[6], ci=vi[2]+vi[6];
    float dr=vr[2]-vr[6], di=vi[2]-vi[6];
    float er=vr[1]+vr[5], ei=vi[1]+vi[5];
    float fr=vr[1]-vr[5], fi=vi[1]-vi[5];
    float gr=vr[3]+vr[7], gi=vi[3]+vi[7];
    float hr=vr[3]-vr[7], hi=vi[3]-vi[7];
    const float W4dr = -sign*di, W4di = sign*dr;
    const float W4hr = -sign*hi, W4hi = sign*hr;
    const float E0r=ar+cr, E0i=ai+ci, E2r=ar-cr, E2i=ai-ci;
    const float E1r=br+W4dr, E1i=bi+W4di, E3r=br-W4dr, E3i=bi-W4di;
    const float O0r=er+gr, O0i=ei+gi, O2r=er-gr, O2i=ei-gi;
    const float O1r=fr+W4hr, O1i=fi+W4hi, O3r=fr-W4hr, O3i=fi-W4hi;
    const float T1r = K*(O1r - sign*O1i), T1i = K*(O1i + sign*O1r);
    const float T2r = -sign*O2i,          T2i = sign*O2r;
    const float T3r = K*(-O3r - sign*O3i), T3i = K*(-O3i + sign*O3r);
    vr[0]=E0r+O0r; vi[0]=E0i+O0i;  vr[4]=E0r-O0r; vi[4]=E0i-O0i;
    vr[1]=E1r+T1r; vi[1]=E1i+T1i;  vr[5]=E1r-T1r; vi[5]=E1i-T1i;
    vr[2]=E2r+T2r; vi[2]=E2i+T2i;  vr[6]=E2r-T2r; vi[6]=E2i-T2i;
    vr[3]=E3r+T3r; vi[3]=E3i+T3i;  vr[7]=E3r-T3r; vi[7]=E3i-T3i;
}

// One Stockham radix-8 pass, IN PLACE, one wave = one FFT (j in 0..63).
// Safe without any barrier: all 8 ds_reads precede all 8 ds_writes in
// program order, and DS ops from one wave are processed in order.
template<int NS>
__device__ __forceinline__ void fft_pass(float* R, float* I, int j, float sign) {
    float vr[8], vi[8];
    #pragma unroll
    for (int r = 0; r < 8; ++r) { vr[r] = R[P(j + 64*r)]; vi[r] = I[P(j + 64*r)]; }
    const float th = sign * (TWO_PI / (8.0f * (float)NS)) * (float)(j & (NS - 1));
    float w1r, w1i; __sincosf(th, &w1i, &w1r);
    float wr = w1r, wi = w1i;
    #pragma unroll
    for (int r = 1; r < 8; ++r) {
        const float tr = vr[r]*wr - vi[r]*wi;
        vi[r] = vr[r]*wi + vi[r]*wr; vr[r] = tr;
        const float nwr = wr*w1r - wi*w1i;
        wi = wr*w1i + wi*w1r; wr = nwr;
    }
    dft8(vr, vi, sign);
    const int base = ((j / NS) * (8 * NS)) + (j & (NS - 1));
    #pragma unroll
    for (int r = 0; r < 8; ++r) { R[P(base + r*NS)] = vr[r]; I[P(base + r*NS)] = vi[r]; }
}

// K1: STFT of BOTH signals via one complex FFT per frame: z = enh + i*noi.
// 4 frames per block (one per wave), wave-autonomous in-place radix-8
// Stockham, ZERO __syncthreads.
__global__ __launch_bounds__(256, 8) void stft_kernel(const float* __restrict__ enh,
                                                      const float* __restrict__ noi,
                                                      float2* __restrict__ e_spec,
                                                      float*  __restrict__ n_mag) {
    __shared__ float Ar[4*FBUF], Ai[4*FBUF];
    const int tid = threadIdx.x;
    const int w = tid >> 6, j = tid & 63;
    const int tr_ = blockIdx.x * 4 + w;
    const bool live = tr_ < NT;
    const int t = live ? tr_ : NT - 1;
    const int b = blockIdx.y;
    float* ar = Ar + w*FBUF; float* ai = Ai + w*FBUF;

    // pass 0: global -> registers (windowed, reflect-padded), dft8, write A
    {
        const int sbase = t * HOP - PADC;
        const float* __restrict__ pe = enh + b * LEN;
        const float* __restrict__ pn = noi + b * LEN;
        float vr[8], vi[8];
        #pragma unroll
        for (int r = 0; r < 8; ++r) {
            const int n = j + 64*r;
            const int idx = reflect_idx(sbase + n);
            const float wd = hann(n);
            vr[r] = pe[idx] * wd;
            vi[r] = pn[idx] * wd;
        }
        dft8(vr, vi, -1.0f);
        #pragma unroll
        for (int r = 0; r < 8; ++r) { ar[P(8*j + r)] = vr[r]; ai[P(8*j + r)] = vi[r]; }
    }
    fft_pass<8> (ar, ai, j, -1.0f);
    fft_pass<64>(ar, ai, j, -1.0f);

    // extract rfft of both signals: X=(Z(k)+conj(Z(512-k)))/2, Y=(Z(k)-conj(Z(512-k)))/2i
    if (live) {
        const int obase = (b * NT + t) * NF;
        #pragma unroll
        for (int r = 0; r < 5; ++r) {
            const int kk = j + 64*r;
            if (kk > 256) break;
            if (r == 4 && j != 0) break;
            const float zr = ar[P(kk)], zi = ai[P(kk)];
            const int n2 = (512 - kk) & 511;
            const float yr = ar[P(n2)], yi = ai[P(n2)];
            const float er = 0.5f*(zr + yr), ei = 0.5f*(zi - yi);
            const float nr = 0.5f*(zi + yi), ni = 0.5f*(yr - zr);
            e_spec[obase + kk] = make_float2(er, ei);
            n_mag[obase + kk] = fmaxf(sqrtf(nr*nr + ni*ni), 1e-6f);
        }
    }
}

// K2: fused rolling-quantile (4th-smallest of 31 along t, edge-replicated)
//     + freq avg-pool k=5 (zero-pad) via LDS. Block = one (b,t) row.
__global__ __launch_bounds__(256) void quantpool_kernel(const float* __restrict__ n_mag,
                                                        float* __restrict__ pooled) {
    __shared__ float q[NF];
    const int tid = threadIdx.x;
    const int t = blockIdx.x, b = blockIdx.y;
    const float* __restrict__ pb = n_mag + b * NT * NF;

    for (int f = tid; f < NF; f += 256) {
        float m0 = 3.4e38f, m1 = 3.4e38f, m2 = 3.4e38f, m3 = 3.4e38f;
        #pragma unroll
        for (int dt = -15; dt <= 15; ++dt) {
            int tt = t + dt;
            tt = tt < 0 ? 0 : (tt > NT - 1 ? NT - 1 : tt);
            const float v = pb[tt * NF + f];
            const float a0 = fminf(m0, v);  const float c0 = fmaxf(m0, v);
            const float a1 = fminf(m1, c0); const float c1 = fmaxf(m1, c0);
            const float a2 = fminf(m2, c1); const float c2 = fmaxf(m2, c1);
            const float a3 = fminf(m3, c2);
            m0 = a0; m1 = a1; m2 = a2; m3 = a3;
        }
        q[f] = m3;
    }
    __syncthreads();

    for (int f = tid; f < NF; f += 256) {
        float acc = 0.0f;
        #pragma unroll
        for (int df = -2; df <= 2; ++df) {
            const int ff = f + df;
            if (ff >= 0 && ff < NF) acc += q[ff];
        }
        pooled[(b * NT + t) * NF + f] = acc * (1.0f / 5.0f);
    }
}

// K3: fused [time-pool k=9 + floor + sigmoid mask + apply] + ISTFT.
// 8 frames per block; each wave handles 2 frames fully independently:
// wave-local staging (rows 2w,2w+1), then in-place packed IFFT inside the
// staging region itself (2*GSTR == FBUF). ZERO __syncthreads.
__global__ __launch_bounds__(256, 8) void istft_kernel(const float2* __restrict__ g,
                                                       const float* __restrict__ pooled,
                                                       float* __restrict__ frames) {
    __shared__ float gr[8*GSTR], gi[8*GSTR];
    const int tid = threadIdx.x;
    const int w = tid >> 6, j = tid & 63;
    const int t0 = blockIdx.x * 8, b = blockIdx.y;
    const int ta = t0 + 2*w, tb = ta + 1;

    float* g0r = gr + (2*w) * GSTR;      float* g0i = gi + (2*w) * GSTR;
    float* g1r = gr + (2*w + 1) * GSTR;  float* g1i = gi + (2*w + 1) * GSTR;

    // mask phase (wave-local): fill this wave's 2 staging rows
    for (int e = j; e < 2 * NF; e += 64) {
        const int h = (e >= NF) ? 1 : 0;
        const int kk = e - h * NF;
        const int t = ta + h;
        float grv = 0.0f, giv = 0.0f;
        if (t < NT) {
            const float* __restrict__ pc = pooled + b * NT * NF + kk;
            float acc = 0.0f;
            #pragma unroll
            for (int dt = -4; dt <= 4; ++dt) {
                const int tt = t + dt;
                if (tt >= 0 && tt < NT) acc += pc[tt * NF];
            }
            const float fl = fmaxf(acc * (1.0f / 9.0f), 1e-6f);
            const float2 e2 = g[(b * NT + t) * NF + kk];
            const float a = sqrtf(e2.x * e2.x + e2.y * e2.y);
            const float emag = fmaxf(a, 1e-6f);
            const float xarg = (emag - 1.5f * fl) / (0.15f * fl + 1e-6f);
            const float mask = 1.0f / (1.0f + __expf(-xarg));
            const float fm = 0.08f + 0.92f * (0.65f + 0.35f * mask);
            const float scale = emag * fm / fmaxf(a, 1e-12f);
            grv = e2.x * scale; giv = e2.y * scale;
        }
        gr[(2*w + h) * GSTR + kk] = grv;
        gi[(2*w + h) * GSTR + kk] = giv;
    }

    float* ar = g0r;   // FFT region = this wave's two staging rows (528 floats)
    float* ai = g0i;

    // pass 0: build packed C(n) = G1full + i*G2full from staging, dft8,
    // write back into the same region (all reads precede all writes).
    {
        float vr[8], vi[8];
        #pragma unroll
        for (int r = 0; r < 8; ++r) {
            const int n = j + 64*r;
            float cr, ci;
            if (n <= 256) {
                cr = g0r[n] - g1i[n];
                ci = g0i[n] + g1r[n];
            } else {
                const int m = 512 - n;
                cr = g0r[m] + g1i[m];
                ci = g1r[m] - g0i[m];
            }
            vr[r] = cr; vi[r] = ci;
        }
        dft8(vr, vi, 1.0f);
        #pragma unroll
        for (int r = 0; r < 8; ++r) { ar[P(8*j + r)] = vr[r]; ai[P(8*j + r)] = vi[r]; }
    }
    fft_pass<8> (ar, ai, j, 1.0f);
    fft_pass<64>(ar, ai, j, 1.0f);

    // x1(n) = Re -> frame ta, x2(n) = Im -> frame tb
    #pragma unroll
    for (int r = 0; r < 8; ++r) {
        const int n = j + 64*r;
        const float wd = hann(n) * (1.0f / 512.0f);
        if (ta < NT) frames[(b * NT + ta) * NFFT + n] = ar[P(n)] * wd;
        if (tb < NT) frames[(b * NT + tb) * NFFT + n] = ai[P(n)] * wd;
    }
}

// K4: overlap-add gather + window-square normalization + crop.
// Interior (4 overlapping frames): sum(hann^2 at hop 128) == 1.5 exactly.
__global__ __launch_bounds__(256) void ola_kernel(const float* __restrict__ frames,
                                                  float* __restrict__ out) {
    const int j = blockIdx.x * 256 + threadIdx.x;
    if (j >= BATCH * LEN) return;
    const int b = j / LEN;
    const int jj = j - b * LEN;
    const int i = jj + PADC;
    int t_lo = (i >= 384) ? ((i - 384) >> 7) : 0;
    int t_hi = i >> 7; if (t_hi > NT - 1) t_hi = NT - 1;
    if (t_hi - t_lo == 3) {
        const float* __restrict__ fp = frames + (b * NT + t_lo) * NFFT + (i - (t_lo << 7));
        const float acc = fp[0] + fp[384] + fp[768] + fp[1152];
        out[j] = acc * (2.0f / 3.0f);
    } else {
        float acc = 0.0f, wacc = 0.0f;
        for (int t = t_lo; t <= t_hi; ++t) {
            const int n = i - (t << 7);
            const float w = hann(n);
            acc  += frames[(b * NT + t) * NFFT + n];
            wacc += w * w;
        }
        out[j] = acc / fmaxf(wacc, 1e-11f);
    }
}

extern "C" void kernel_launch(void* const* d_in, const int* in_sizes, int n_in,
                              void* d_out, int out_size, void* d_ws, size_t ws_size,
                              hipStream_t stream) {
    const float* noisy    = (const float*)d_in[0];
    const float* enhanced = (const float*)d_in[1];
    float* out = (float*)d_out;

    // workspace layout (floats), total 25680528 (~102.7 MB):
    //   e_spec : [0, 10288224)              (16*1251*257 float2)
    //   pooled : [10288224, 15432336)
    //   n_mag  : [15432336, 20576448)       (dead after quantpool)
    //   frames : [15432336, 25680528)       (reuses dead n_mag region)
    float* ws = (float*)d_ws;
    float2* e_spec = (float2*)ws;
    float* pooled = ws + 10288224;
    float* n_mag  = ws + 15432336;
    float* frames = ws + 15432336;

    dim3 blk(256);
    stft_kernel     <<<dim3((NT + 3) / 4, BATCH), blk, 0, stream>>>(enhanced, noisy, e_spec, n_mag);
    quantpool_kernel<<<dim3(NT, BATCH), blk, 0, stream>>>(n_mag, pooled);
    istft_kernel    <<<dim3((NT + 7) / 8, BATCH), blk, 0, stream>>>(e_spec, pooled, frames);
    ola_kernel      <<<dim3((BATCH * LEN + 255) / 256), blk, 0, stream>>>(frames, out);
}

// Round 6
// 185.927 us; speedup vs baseline: 2.5516x; 1.1417x over previous
//
#include <hip/hip_runtime.h>
#include <math.h>

#define BATCH 16
#define LEN   160000
#define NFFT  512
#define HOP   128
#define NT    1251      // 1 + (160000+512-512)/128
#define NF    257
#define PADC  256
#define TWO_PI 6.28318530717958647692f
// padded LDS index: +1 float per 32 -> breaks power-of-2 bank aliasing
#define P(i) ((i) + ((i) >> 5))
#define FBUF 528        // padded 512-float FFT region (P(511)=526 < 528)
#define GSTR 264        // staging row stride: 2 rows == FBUF exactly

__device__ __forceinline__ int reflect_idx(int j) {
    j = j < 0 ? -j : j;
    j = j >= LEN ? 2*LEN - 2 - j : j;
    return j;
}

__device__ __forceinline__ float hann(int n) {
    return 0.5f - 0.5f * __cosf(TWO_PI * (float)n * (1.0f / 512.0f));
}

// 8-point DFT in registers. y[m] = sum_r v[r] * exp(sign*2*pi*i*r*m/8).
__device__ __forceinline__ void dft8(float vr[8], float vi[8], float sign) {
    const float K = 0.70710678118654752f;
    float ar=vr[0]+vr[4], ai=vi[0]+vi[4];
    float br=vr[0]-vr[4], bi=vi[0]-vi[4];
    float cr=vr[2]+vr[6], ci=vi[2]+vi[6];
    float dr=vr[2]-vr[6], di=vi[2]-vi[6];
    float er=vr[1]+vr[5], ei=vi[1]+vi[5];
    float fr=vr[1]-vr[5], fi=vi[1]-vi[5];
    float gr=vr[3]+vr[7], gi=vi[3]+vi[7];
    float hr=vr[3]-vr[7], hi=vi[3]-vi[7];
    const float W4dr = -sign*di, W4di = sign*dr;
    const float W4hr = -sign*hi, W4hi = sign*hr;
    const float E0r=ar+cr, E0i=ai+ci, E2r=ar-cr, E2i=ai-ci;
    const float E1r=br+W4dr, E1i=bi+W4di, E3r=br-W4dr, E3i=bi-W4di;
    const float O0r=er+gr, O0i=ei+gi, O2r=er-gr, O2i=ei-gi;
    const float O1r=fr+W4hr, O1i=fi+W4hi, O3r=fr-W4hr, O3i=fi-W4hi;
    const float T1r = K*(O1r - sign*O1i), T1i = K*(O1i + sign*O1r);
    const float T2r = -sign*O2i,          T2i = sign*O2r;
    const float T3r = K*(-O3r - sign*O3i), T3i = K*(-O3i + sign*O3r);
    vr[0]=E0r+O0r; vi[0]=E0i+O0i;  vr[4]=E0r-O0r; vi[4]=E0i-O0i;
    vr[1]=E1r+T1r; vi[1]=E1i+T1i;  vr[5]=E1r-T1r; vi[5]=E1i-T1i;
    vr[2]=E2r+T2r; vi[2]=E2i+T2i;  vr[6]=E2r-T2r; vi[6]=E2i-T2i;
    vr[3]=E3r+T3r; vi[3]=E3i+T3i;  vr[7]=E3r-T3r; vi[7]=E3i-T3i;
}

// One Stockham radix-8 pass, IN PLACE, one wave = one FFT (j in 0..63).
// Safe without any barrier: all 8 ds_reads precede all 8 ds_writes in
// program order, and DS ops from one wave are processed in order.
template<int NS>
__device__ __forceinline__ void fft_pass(float* R, float* I, int j, float sign) {
    float vr[8], vi[8];
    #pragma unroll
    for (int r = 0; r < 8; ++r) { vr[r] = R[P(j + 64*r)]; vi[r] = I[P(j + 64*r)]; }
    const float th = sign * (TWO_PI / (8.0f * (float)NS)) * (float)(j & (NS - 1));
    float w1r, w1i; __sincosf(th, &w1i, &w1r);
    float wr = w1r, wi = w1i;
    #pragma unroll
    for (int r = 1; r < 8; ++r) {
        const float tr = vr[r]*wr - vi[r]*wi;
        vi[r] = vr[r]*wi + vi[r]*wr; vr[r] = tr;
        const float nwr = wr*w1r - wi*w1i;
        wi = wr*w1i + wi*w1r; wr = nwr;
    }
    dft8(vr, vi, sign);
    const int base = ((j / NS) * (8 * NS)) + (j & (NS - 1));
    #pragma unroll
    for (int r = 0; r < 8; ++r) { R[P(base + r*NS)] = vr[r]; I[P(base + r*NS)] = vi[r]; }
}

// K1: STFT of BOTH signals via one complex FFT per frame: z = enh + i*noi.
// 4 frames per block (one per wave), wave-autonomous in-place radix-8
// Stockham, ZERO __syncthreads.
__global__ __launch_bounds__(256, 4) void stft_kernel(const float* __restrict__ enh,
                                                      const float* __restrict__ noi,
                                                      float2* __restrict__ e_spec,
                                                      float*  __restrict__ n_mag) {
    __shared__ float Ar[4*FBUF], Ai[4*FBUF];
    const int tid = threadIdx.x;
    const int w = tid >> 6, j = tid & 63;
    const int tr_ = blockIdx.x * 4 + w;
    const bool live = tr_ < NT;
    const int t = live ? tr_ : NT - 1;
    const int b = blockIdx.y;
    float* ar = Ar + w*FBUF; float* ai = Ai + w*FBUF;

    // pass 0: global -> registers (windowed, reflect-padded), dft8, write A
    {
        const int sbase = t * HOP - PADC;
        const float* __restrict__ pe = enh + b * LEN;
        const float* __restrict__ pn = noi + b * LEN;
        float vr[8], vi[8];
        #pragma unroll
        for (int r = 0; r < 8; ++r) {
            const int n = j + 64*r;
            const int idx = reflect_idx(sbase + n);
            const float wd = hann(n);
            vr[r] = pe[idx] * wd;
            vi[r] = pn[idx] * wd;
        }
        dft8(vr, vi, -1.0f);
        #pragma unroll
        for (int r = 0; r < 8; ++r) { ar[P(8*j + r)] = vr[r]; ai[P(8*j + r)] = vi[r]; }
    }
    fft_pass<8> (ar, ai, j, -1.0f);
    fft_pass<64>(ar, ai, j, -1.0f);

    // extract rfft of both signals: X=(Z(k)+conj(Z(512-k)))/2, Y=(Z(k)-conj(Z(512-k)))/2i
    if (live) {
        const int obase = (b * NT + t) * NF;
        #pragma unroll
        for (int r = 0; r < 5; ++r) {
            const int kk = j + 64*r;
            if (kk > 256) break;
            if (r == 4 && j != 0) break;
            const float zr = ar[P(kk)], zi = ai[P(kk)];
            const int n2 = (512 - kk) & 511;
            const float yr = ar[P(n2)], yi = ai[P(n2)];
            const float er = 0.5f*(zr + yr), ei = 0.5f*(zi - yi);
            const float nr = 0.5f*(zi + yi), ni = 0.5f*(yr - zr);
            e_spec[obase + kk] = make_float2(er, ei);
            n_mag[obase + kk] = fmaxf(sqrtf(nr*nr + ni*ni), 1e-6f);
        }
    }
}

// K2: FULLY fused floor: rolling quantile (4th-smallest of 31 along t,
// edge-replicated) -> freq avg-pool k=5 (zero-pad) -> time avg-pool k=9
// (zero-pad) -> clamp 1e-6. Block = (t-tile of 8 outputs, b). Each thread
// holds the 54-row n_mag column for its f in REGISTERS and emits 16
// quantile rows (outputs' t +/-4 halo) to LDS; pools run from LDS.
__global__ __launch_bounds__(256) void floor_kernel(const float* __restrict__ n_mag,
                                                    float* __restrict__ floor_) {
    __shared__ float q[16][GSTR];
    const int tid = threadIdx.x;
    const int t0 = blockIdx.x * 8, b = blockIdx.y;
    const float* __restrict__ pb = n_mag + b * NT * NF;

    // quantile rows k=0..15 (tq = t0-4+k) for f = tid
    {
        float wv[54];
        #pragma unroll
        for (int r = 0; r < 54; ++r) {
            int tr = t0 - 19 + r;
            tr = tr < 0 ? 0 : (tr > NT - 1 ? NT - 1 : tr);
            wv[r] = pb[tr * NF + tid];
        }
        #pragma unroll
        for (int k = 0; k < 16; ++k) {
            float m0 = 3.4e38f, m1 = 3.4e38f, m2 = 3.4e38f, m3 = 3.4e38f;
            #pragma unroll
            for (int r = k; r < k + 31; ++r) {
                const float v = wv[r];
                const float a0 = fminf(m0, v);  const float c0 = fmaxf(m0, v);
                const float a1 = fminf(m1, c0); const float c1 = fmaxf(m1, c0);
                const float a2 = fminf(m2, c1); const float c2 = fmaxf(m2, c1);
                const float a3 = fminf(m3, c2);
                m0 = a0; m1 = a1; m2 = a2; m3 = a3;
            }
            q[k][tid] = m3;
        }
    }
    // f = 256 column: threads 0..15 each compute one quantile row
    if (tid < 16) {
        const int k = tid;
        float m0 = 3.4e38f, m1 = 3.4e38f, m2 = 3.4e38f, m3 = 3.4e38f;
        for (int dt = -15; dt <= 15; ++dt) {
            int tt = t0 - 4 + k + dt;
            tt = tt < 0 ? 0 : (tt > NT - 1 ? NT - 1 : tt);
            const float v = pb[tt * NF + 256];
            const float a0 = fminf(m0, v);  const float c0 = fmaxf(m0, v);
            const float a1 = fminf(m1, c0); const float c1 = fmaxf(m1, c0);
            const float a2 = fminf(m2, c1); const float c2 = fmaxf(m2, c1);
            const float a3 = fminf(m3, c2);
            m0 = a0; m1 = a1; m2 = a2; m3 = a3;
        }
        q[k][256] = m3;
    }
    __syncthreads();

    // freq pool k=5 zero-pad into registers
    float fp[16];
    {
        const int f = tid;
        #pragma unroll
        for (int k = 0; k < 16; ++k) {
            float acc = 0.0f;
            #pragma unroll
            for (int df = -2; df <= 2; ++df) {
                const int ff = f + df;
                if (ff >= 0 && ff < NF) acc += q[k][ff];
            }
            fp[k] = acc * (1.0f / 5.0f);
        }
    }
    float fp256 = 0.0f;
    if (tid >= 16 && tid < 32) {
        const int k = tid - 16;
        float acc = 0.0f;
        #pragma unroll
        for (int df = -2; df <= 2; ++df) {
            const int ff = 256 + df;
            if (ff < NF) acc += q[k][ff];
        }
        fp256 = acc * (1.0f / 5.0f);
    }
    __syncthreads();

    // write back freq-pooled rows; rows with tq outside [0,NT) act as ZERO
    // in the (zero-padded) time pool.
    #pragma unroll
    for (int k = 0; k < 16; ++k) {
        const int tq = t0 - 4 + k;
        q[k][tid] = (tq >= 0 && tq < NT) ? fp[k] : 0.0f;
    }
    if (tid >= 16 && tid < 32) {
        const int k = tid - 16;
        const int tq = t0 - 4 + k;
        q[k][256] = (tq >= 0 && tq < NT) ? fp256 : 0.0f;
    }
    __syncthreads();

    // time pool k=9 + clamp + store final floor
    for (int f = tid; f < NF; f += 256) {
        #pragma unroll
        for (int to = 0; to < 8; ++to) {
            const int t = t0 + to;
            if (t >= NT) break;
            float acc = 0.0f;
            #pragma unroll
            for (int k = to; k < to + 9; ++k) acc += q[k][f];
            floor_[(b * NT + t) * NF + f] = fmaxf(acc * (1.0f / 9.0f), 1e-6f);
        }
    }
}

// K3: fused [sigmoid mask from precomputed floor + apply] + ISTFT.
// 8 frames per block; each wave handles 2 frames fully independently:
// wave-local staging (rows 2w,2w+1), then in-place packed IFFT inside the
// staging region itself (2*GSTR == FBUF). ZERO __syncthreads.
__global__ __launch_bounds__(256, 4) void istft_kernel(const float2* __restrict__ g,
                                                       const float* __restrict__ floor_,
                                                       float* __restrict__ frames) {
    __shared__ float gr[8*GSTR], gi[8*GSTR];
    const int tid = threadIdx.x;
    const int w = tid >> 6, j = tid & 63;
    const int t0 = blockIdx.x * 8, b = blockIdx.y;
    const int ta = t0 + 2*w, tb = ta + 1;

    float* g0r = gr + (2*w) * GSTR;      float* g0i = gi + (2*w) * GSTR;
    float* g1r = gr + (2*w + 1) * GSTR;  float* g1i = gi + (2*w + 1) * GSTR;

    // mask phase (wave-local): fill this wave's 2 staging rows
    for (int e = j; e < 2 * NF; e += 64) {
        const int h = (e >= NF) ? 1 : 0;
        const int kk = e - h * NF;
        const int t = ta + h;
        float grv = 0.0f, giv = 0.0f;
        if (t < NT) {
            const int idx = (b * NT + t) * NF + kk;
            const float fl = floor_[idx];
            const float2 e2 = g[idx];
            const float a = sqrtf(e2.x * e2.x + e2.y * e2.y);
            const float emag = fmaxf(a, 1e-6f);
            const float xarg = (emag - 1.5f * fl) / (0.15f * fl + 1e-6f);
            const float mask = 1.0f / (1.0f + __expf(-xarg));
            const float fm = 0.08f + 0.92f * (0.65f + 0.35f * mask);
            const float scale = emag * fm / fmaxf(a, 1e-12f);
            grv = e2.x * scale; giv = e2.y * scale;
        }
        gr[(2*w + h) * GSTR + kk] = grv;
        gi[(2*w + h) * GSTR + kk] = giv;
    }

    float* ar = g0r;   // FFT region = this wave's two staging rows (528 floats)
    float* ai = g0i;

    // pass 0: build packed C(n) = G1full + i*G2full from staging, dft8,
    // write back into the same region (all reads precede all writes).
    {
        float vr[8], vi[8];
        #pragma unroll
        for (int r = 0; r < 8; ++r) {
            const int n = j + 64*r;
            float cr, ci;
            if (n <= 256) {
                cr = g0r[n] - g1i[n];
                ci = g0i[n] + g1r[n];
            } else {
                const int m = 512 - n;
                cr = g0r[m] + g1i[m];
                ci = g1r[m] - g0i[m];
            }
            vr[r] = cr; vi[r] = ci;
        }
        dft8(vr, vi, 1.0f);
        #pragma unroll
        for (int r = 0; r < 8; ++r) { ar[P(8*j + r)] = vr[r]; ai[P(8*j + r)] = vi[r]; }
    }
    fft_pass<8> (ar, ai, j, 1.0f);
    fft_pass<64>(ar, ai, j, 1.0f);

    // x1(n) = Re -> frame ta, x2(n) = Im -> frame tb
    #pragma unroll
    for (int r = 0; r < 8; ++r) {
        const int n = j + 64*r;
        const float wd = hann(n) * (1.0f / 512.0f);
        if (ta < NT) frames[(b * NT + ta) * NFFT + n] = ar[P(n)] * wd;
        if (tb < NT) frames[(b * NT + tb) * NFFT + n] = ai[P(n)] * wd;
    }
}

// K4: overlap-add gather + window-square normalization + crop.
// Interior (4 overlapping frames): sum(hann^2 at hop 128) == 1.5 exactly.
__global__ __launch_bounds__(256) void ola_kernel(const float* __restrict__ frames,
                                                  float* __restrict__ out) {
    const int j = blockIdx.x * 256 + threadIdx.x;
    if (j >= BATCH * LEN) return;
    const int b = j / LEN;
    const int jj = j - b * LEN;
    const int i = jj + PADC;
    int t_lo = (i >= 384) ? ((i - 384) >> 7) : 0;
    int t_hi = i >> 7; if (t_hi > NT - 1) t_hi = NT - 1;
    if (t_hi - t_lo == 3) {
        const float* __restrict__ fp = frames + (b * NT + t_lo) * NFFT + (i - (t_lo << 7));
        const float acc = fp[0] + fp[384] + fp[768] + fp[1152];
        out[j] = acc * (2.0f / 3.0f);
    } else {
        float acc = 0.0f, wacc = 0.0f;
        for (int t = t_lo; t <= t_hi; ++t) {
            const int n = i - (t << 7);
            const float w = hann(n);
            acc  += frames[(b * NT + t) * NFFT + n];
            wacc += w * w;
        }
        out[j] = acc / fmaxf(wacc, 1e-11f);
    }
}

extern "C" void kernel_launch(void* const* d_in, const int* in_sizes, int n_in,
                              void* d_out, int out_size, void* d_ws, size_t ws_size,
                              hipStream_t stream) {
    const float* noisy    = (const float*)d_in[0];
    const float* enhanced = (const float*)d_in[1];
    float* out = (float*)d_out;

    // workspace layout (floats), total 25680528 (~102.7 MB):
    //   e_spec : [0, 10288224)              (16*1251*257 float2)
    //   floor  : [10288224, 15432336)
    //   n_mag  : [15432336, 20576448)       (dead after floor_kernel)
    //   frames : [15432336, 25680528)       (reuses dead n_mag region)
    float* ws = (float*)d_ws;
    float2* e_spec = (float2*)ws;
    float* floor_ = ws + 10288224;
    float* n_mag  = ws + 15432336;
    float* frames = ws + 15432336;

    dim3 blk(256);
    stft_kernel <<<dim3((NT + 3) / 4, BATCH), blk, 0, stream>>>(enhanced, noisy, e_spec, n_mag);
    floor_kernel<<<dim3((NT + 7) / 8, BATCH), blk, 0, stream>>>(n_mag, floor_);
    istft_kernel<<<dim3((NT + 7) / 8, BATCH), blk, 0, stream>>>(e_spec, floor_, frames);
    ola_kernel  <<<dim3((BATCH * LEN + 255) / 256), blk, 0, stream>>>(frames, out);
}

// Round 7
// 146.246 us; speedup vs baseline: 3.2439x; 1.2713x over previous
//
#include <hip/hip_runtime.h>
#include <math.h>

#define BATCH 16
#define LEN   160000
#define NFFT  512
#define HOP   128
#define NT    1251      // 1 + (160000+512-512)/128
#define NF    257
#define PADC  256
#define TWO_PI 6.28318530717958647692f
// padded LDS index: +1 float per 32 -> breaks power-of-2 bank aliasing
#define P(i) ((i) + ((i) >> 5))
#define FBUF 528        // padded 512-float FFT region (P(511)=526 < 528)
#define GSTR 264        // staging row stride: 2 rows == FBUF exactly

__device__ __forceinline__ int reflect_idx(int j) {
    j = j < 0 ? -j : j;
    j = j >= LEN ? 2*LEN - 2 - j : j;
    return j;
}

__device__ __forceinline__ float hann(int n) {
    return 0.5f - 0.5f * __cosf(TWO_PI * (float)n * (1.0f / 512.0f));
}

// ---------- sorted-4-smallest tuple machinery (exact, branchless) ----------
struct T4 { float m0, m1, m2, m3; };   // ascending

// insert v keeping the 4 smallest, sorted (7 ops)
__device__ __forceinline__ void ins(T4& a, float v) {
    const float x0 = fminf(a.m0, v);  const float c0 = fmaxf(a.m0, v);
    const float x1 = fminf(a.m1, c0); const float c1 = fmaxf(a.m1, c0);
    const float x2 = fminf(a.m2, c1); const float c2 = fmaxf(a.m2, c1);
    const float x3 = fminf(a.m3, c2);
    a.m0 = x0; a.m1 = x1; a.m2 = x2; a.m3 = x3;
}

// 4 smallest of two sorted-4 tuples, sorted (bitonic, 12 ops)
__device__ __forceinline__ T4 merge4(const T4& a, const T4& b) {
    const float l0 = fminf(a.m0, b.m3);
    const float l1 = fminf(a.m1, b.m2);
    const float l2 = fminf(a.m2, b.m1);
    const float l3 = fminf(a.m3, b.m0);
    const float t0 = fminf(l0, l2), t2 = fmaxf(l0, l2);
    const float t1 = fminf(l1, l3), t3 = fmaxf(l1, l3);
    T4 r;
    r.m0 = fminf(t0, t1); r.m1 = fmaxf(t0, t1);
    r.m2 = fminf(t2, t3); r.m3 = fmaxf(t2, t3);
    return r;
}

// full sort of 4 elements (5 comparators, 10 ops)
__device__ __forceinline__ T4 sort4(float a, float b, float c, float d) {
    const float x0 = fminf(a, b), x1 = fmaxf(a, b);
    const float x2 = fminf(c, d), x3 = fmaxf(c, d);
    const float y0 = fminf(x0, x2), y2 = fmaxf(x0, x2);
    const float y1 = fminf(x1, x3), y3 = fmaxf(x1, x3);
    T4 r; r.m0 = y0; r.m1 = fminf(y1, y2); r.m2 = fmaxf(y1, y2); r.m3 = y3;
    return r;
}

// 8-point DFT in registers. y[m] = sum_r v[r] * exp(sign*2*pi*i*r*m/8).
__device__ __forceinline__ void dft8(float vr[8], float vi[8], float sign) {
    const float K = 0.70710678118654752f;
    float ar=vr[0]+vr[4], ai=vi[0]+vi[4];
    float br=vr[0]-vr[4], bi=vi[0]-vi[4];
    float cr=vr[2]+vr[6], ci=vi[2]+vi[6];
    float dr=vr[2]-vr[6], di=vi[2]-vi[6];
    float er=vr[1]+vr[5], ei=vi[1]+vi[5];
    float fr=vr[1]-vr[5], fi=vi[1]-vi[5];
    float gr=vr[3]+vr[7], gi=vi[3]+vi[7];
    float hr=vr[3]-vr[7], hi=vi[3]-vi[7];
    const float W4dr = -sign*di, W4di = sign*dr;
    const float W4hr = -sign*hi, W4hi = sign*hr;
    const float E0r=ar+cr, E0i=ai+ci, E2r=ar-cr, E2i=ai-ci;
    const float E1r=br+W4dr, E1i=bi+W4di, E3r=br-W4dr, E3i=bi-W4di;
    const float O0r=er+gr, O0i=ei+gi, O2r=er-gr, O2i=ei-gi;
    const float O1r=fr+W4hr, O1i=fi+W4hi, O3r=fr-W4hr, O3i=fi-W4hi;
    const float T1r = K*(O1r - sign*O1i), T1i = K*(O1i + sign*O1r);
    const float T2r = -sign*O2i,          T2i = sign*O2r;
    const float T3r = K*(-O3r - sign*O3i), T3i = K*(-O3i + sign*O3r);
    vr[0]=E0r+O0r; vi[0]=E0i+O0i;  vr[4]=E0r-O0r; vi[4]=E0i-O0i;
    vr[1]=E1r+T1r; vi[1]=E1i+T1i;  vr[5]=E1r-T1r; vi[5]=E1i-T1i;
    vr[2]=E2r+T2r; vi[2]=E2i+T2i;  vr[6]=E2r-T2r; vi[6]=E2i-T2i;
    vr[3]=E3r+T3r; vi[3]=E3i+T3i;  vr[7]=E3r-T3r; vi[7]=E3i-T3i;
}

// One Stockham radix-8 pass, IN PLACE, one wave = one FFT (j in 0..63).
// Safe without any barrier: all 8 ds_reads precede all 8 ds_writes in
// program order, and DS ops from one wave are processed in order.
template<int NS>
__device__ __forceinline__ void fft_pass(float* R, float* I, int j, float sign) {
    float vr[8], vi[8];
    #pragma unroll
    for (int r = 0; r < 8; ++r) { vr[r] = R[P(j + 64*r)]; vi[r] = I[P(j + 64*r)]; }
    const float th = sign * (TWO_PI / (8.0f * (float)NS)) * (float)(j & (NS - 1));
    float w1r, w1i; __sincosf(th, &w1i, &w1r);
    float wr = w1r, wi = w1i;
    #pragma unroll
    for (int r = 1; r < 8; ++r) {
        const float tr = vr[r]*wr - vi[r]*wi;
        vi[r] = vr[r]*wi + vi[r]*wr; vr[r] = tr;
        const float nwr = wr*w1r - wi*w1i;
        wi = wr*w1i + wi*w1r; wr = nwr;
    }
    dft8(vr, vi, sign);
    const int base = ((j / NS) * (8 * NS)) + (j & (NS - 1));
    #pragma unroll
    for (int r = 0; r < 8; ++r) { R[P(base + r*NS)] = vr[r]; I[P(base + r*NS)] = vi[r]; }
}

// K1: STFT of BOTH signals via one complex FFT per frame: z = enh + i*noi.
// 4 frames per block (one per wave), wave-autonomous in-place radix-8
// Stockham, ZERO __syncthreads.
__global__ __launch_bounds__(256, 4) void stft_kernel(const float* __restrict__ enh,
                                                      const float* __restrict__ noi,
                                                      float2* __restrict__ e_spec,
                                                      float*  __restrict__ n_mag) {
    __shared__ float Ar[4*FBUF], Ai[4*FBUF];
    const int tid = threadIdx.x;
    const int w = tid >> 6, j = tid & 63;
    const int tr_ = blockIdx.x * 4 + w;
    const bool live = tr_ < NT;
    const int t = live ? tr_ : NT - 1;
    const int b = blockIdx.y;
    float* ar = Ar + w*FBUF; float* ai = Ai + w*FBUF;

    // pass 0: global -> registers (windowed, reflect-padded), dft8, write A
    {
        const int sbase = t * HOP - PADC;
        const float* __restrict__ pe = enh + b * LEN;
        const float* __restrict__ pn = noi + b * LEN;
        float vr[8], vi[8];
        #pragma unroll
        for (int r = 0; r < 8; ++r) {
            const int n = j + 64*r;
            const int idx = reflect_idx(sbase + n);
            const float wd = hann(n);
            vr[r] = pe[idx] * wd;
            vi[r] = pn[idx] * wd;
        }
        dft8(vr, vi, -1.0f);
        #pragma unroll
        for (int r = 0; r < 8; ++r) { ar[P(8*j + r)] = vr[r]; ai[P(8*j + r)] = vi[r]; }
    }
    fft_pass<8> (ar, ai, j, -1.0f);
    fft_pass<64>(ar, ai, j, -1.0f);

    // extract rfft of both signals: X=(Z(k)+conj(Z(512-k)))/2, Y=(Z(k)-conj(Z(512-k)))/2i
    if (live) {
        const int obase = (b * NT + t) * NF;
        #pragma unroll
        for (int r = 0; r < 5; ++r) {
            const int kk = j + 64*r;
            if (kk > 256) break;
            if (r == 4 && j != 0) break;
            const float zr = ar[P(kk)], zi = ai[P(kk)];
            const int n2 = (512 - kk) & 511;
            const float yr = ar[P(n2)], yi = ai[P(n2)];
            const float er = 0.5f*(zr + yr), ei = 0.5f*(zi - yi);
            const float nr = 0.5f*(zi + yi), ni = 0.5f*(yr - zr);
            e_spec[obase + kk] = make_float2(er, ei);
            n_mag[obase + kk] = fmaxf(sqrtf(nr*nr + ni*ni), 1e-6f);
        }
    }
}

// K2: FULLY fused floor. Tile = 16 outputs (24 quantile rows incl. +/-4
// halo; 54-element time window in registers). Quantile = 4th-smallest of
// 31 via chunked selection: sorted-4 of aligned 8-chunks + 2 bitonic
// merges + exactly 7 element inserts per window (81 ops vs 217 naive).
// Freq-pool k=5 via LDS; time-pool k=9 as per-thread sliding 9-sum.
__global__ __launch_bounds__(256) void floor_kernel(const float* __restrict__ n_mag,
                                                    float* __restrict__ floor_) {
    __shared__ float q[24][GSTR];
    __shared__ float fq[24];
    const int tid = threadIdx.x;
    const int t0 = blockIdx.x * 16, b = blockIdx.y;
    const float* __restrict__ pb = n_mag + b * NT * NF;

    // ---- phase A: quantile rows k=0..23 (tq = t0-4+k) for f = tid ----
    {
        float wv[54];
        #pragma unroll
        for (int r = 0; r < 54; ++r) {
            int tr = t0 - 19 + r;
            tr = tr < 0 ? 0 : (tr > NT - 1 ? NT - 1 : tr);
            wv[r] = pb[tr * NF + tid];
        }
        T4 ch[6];
        #pragma unroll
        for (int c = 0; c < 6; ++c)
            ch[c] = merge4(sort4(wv[8*c],   wv[8*c+1], wv[8*c+2], wv[8*c+3]),
                           sort4(wv[8*c+4], wv[8*c+5], wv[8*c+6], wv[8*c+7]));
        #pragma unroll
        for (int k = 0; k < 24; ++k) {
            const int c0 = (k + 7) >> 3;      // full chunks c0, c0+1, c0+2
            T4 m = merge4(merge4(ch[c0], ch[c0+1]), ch[c0+2]);
            #pragma unroll
            for (int jj = k; jj < 8*c0; ++jj) ins(m, wv[jj]);        // head
            #pragma unroll
            for (int jj = 8*c0 + 24; jj < k + 31; ++jj) ins(m, wv[jj]); // tail
            q[k][tid] = m.m3;
        }
    }
    // f = 256 column: threads 0..23, one quantile row each (naive 31-insert)
    if (tid < 24) {
        const int k = tid;
        T4 m; m.m0 = m.m1 = m.m2 = m.m3 = 3.4e38f;
        for (int dt = -15; dt <= 15; ++dt) {
            int tt = t0 - 4 + k + dt;
            tt = tt < 0 ? 0 : (tt > NT - 1 ? NT - 1 : tt);
            ins(m, pb[tt * NF + 256]);
        }
        q[k][256] = m.m3;
    }
    __syncthreads();

    // ---- phase B: freq pool k=5 (zero-pad) into registers ----
    float fp[24];
    {
        const int f = tid;
        #pragma unroll
        for (int k = 0; k < 24; ++k) {
            float acc = 0.0f;
            #pragma unroll
            for (int df = -2; df <= 2; ++df) {
                const int ff = f + df;
                if (ff >= 0 && ff < NF) acc += q[k][ff];
            }
            fp[k] = acc * (1.0f / 5.0f);
        }
    }
    if (tid < 24) {   // f = 256 pooled rows -> fq
        const int k = tid;
        fq[k] = (q[k][254] + q[k][255] + q[k][256]) * (1.0f / 5.0f);
    }
    __syncthreads();

    // ---- phase C: zero out-of-range rows, time pool k=9 sliding, store ----
    {
        const int f = tid;
        #pragma unroll
        for (int k = 0; k < 24; ++k) {
            const int tq = t0 - 4 + k;
            fp[k] = (tq >= 0 && tq < NT) ? fp[k] : 0.0f;
        }
        float acc = 0.0f;
        #pragma unroll
        for (int k = 0; k < 9; ++k) acc += fp[k];
        #pragma unroll
        for (int to = 0; to < 16; ++to) {
            const int t = t0 + to;
            if (t < NT)
                floor_[(b * NT + t) * NF + f] = fmaxf(acc * (1.0f / 9.0f), 1e-6f);
            if (to < 15) acc += fp[to + 9] - fp[to];
        }
    }
    if (tid < 16) {   // f = 256 outputs
        const int to = tid;
        const int t = t0 + to;
        if (t < NT) {
            float acc = 0.0f;
            #pragma unroll
            for (int k = 0; k < 9; ++k) {
                const int tq = t0 - 4 + to + k;
                acc += (tq >= 0 && tq < NT) ? fq[to + k] : 0.0f;
            }
            floor_[(b * NT + t) * NF + 256] = fmaxf(acc * (1.0f / 9.0f), 1e-6f);
        }
    }
}

// K3: fused [sigmoid mask from precomputed floor + apply] + ISTFT.
// 8 frames per block; each wave handles 2 frames fully independently:
// wave-local staging (rows 2w,2w+1), then in-place packed IFFT inside the
// staging region itself (2*GSTR == FBUF). ZERO __syncthreads.
__global__ __launch_bounds__(256, 4) void istft_kernel(const float2* __restrict__ g,
                                                       const float* __restrict__ floor_,
                                                       float* __restrict__ frames) {
    __shared__ float gr[8*GSTR], gi[8*GSTR];
    const int tid = threadIdx.x;
    const int w = tid >> 6, j = tid & 63;
    const int t0 = blockIdx.x * 8, b = blockIdx.y;
    const int ta = t0 + 2*w, tb = ta + 1;

    float* g0r = gr + (2*w) * GSTR;      float* g0i = gi + (2*w) * GSTR;
    float* g1r = gr + (2*w + 1) * GSTR;  float* g1i = gi + (2*w + 1) * GSTR;

    // mask phase (wave-local): fill this wave's 2 staging rows
    for (int e = j; e < 2 * NF; e += 64) {
        const int h = (e >= NF) ? 1 : 0;
        const int kk = e - h * NF;
        const int t = ta + h;
        float grv = 0.0f, giv = 0.0f;
        if (t < NT) {
            const int idx = (b * NT + t) * NF + kk;
            const float fl = floor_[idx];
            const float2 e2 = g[idx];
            const float a = sqrtf(e2.x * e2.x + e2.y * e2.y);
            const float emag = fmaxf(a, 1e-6f);
            const float xarg = (emag - 1.5f * fl) / (0.15f * fl + 1e-6f);
            const float mask = 1.0f / (1.0f + __expf(-xarg));
            const float fm = 0.08f + 0.92f * (0.65f + 0.35f * mask);
            const float scale = emag * fm / fmaxf(a, 1e-12f);
            grv = e2.x * scale; giv = e2.y * scale;
        }
        gr[(2*w + h) * GSTR + kk] = grv;
        gi[(2*w + h) * GSTR + kk] = giv;
    }

    float* ar = g0r;   // FFT region = this wave's two staging rows (528 floats)
    float* ai = g0i;

    // pass 0: build packed C(n) = G1full + i*G2full from staging, dft8,
    // write back into the same region (all reads precede all writes).
    {
        float vr[8], vi[8];
        #pragma unroll
        for (int r = 0; r < 8; ++r) {
            const int n = j + 64*r;
            float cr, ci;
            if (n <= 256) {
                cr = g0r[n] - g1i[n];
                ci = g0i[n] + g1r[n];
            } else {
                const int m = 512 - n;
                cr = g0r[m] + g1i[m];
                ci = g1r[m] - g0i[m];
            }
            vr[r] = cr; vi[r] = ci;
        }
        dft8(vr, vi, 1.0f);
        #pragma unroll
        for (int r = 0; r < 8; ++r) { ar[P(8*j + r)] = vr[r]; ai[P(8*j + r)] = vi[r]; }
    }
    fft_pass<8> (ar, ai, j, 1.0f);
    fft_pass<64>(ar, ai, j, 1.0f);

    // x1(n) = Re -> frame ta, x2(n) = Im -> frame tb
    #pragma unroll
    for (int r = 0; r < 8; ++r) {
        const int n = j + 64*r;
        const float wd = hann(n) * (1.0f / 512.0f);
        if (ta < NT) frames[(b * NT + ta) * NFFT + n] = ar[P(n)] * wd;
        if (tb < NT) frames[(b * NT + tb) * NFFT + n] = ai[P(n)] * wd;
    }
}

// K4: overlap-add gather + window-square normalization + crop.
// Interior (4 overlapping frames): sum(hann^2 at hop 128) == 1.5 exactly.
__global__ __launch_bounds__(256) void ola_kernel(const float* __restrict__ frames,
                                                  float* __restrict__ out) {
    const int j = blockIdx.x * 256 + threadIdx.x;
    if (j >= BATCH * LEN) return;
    const int b = j / LEN;
    const int jj = j - b * LEN;
    const int i = jj + PADC;
    int t_lo = (i >= 384) ? ((i - 384) >> 7) : 0;
    int t_hi = i >> 7; if (t_hi > NT - 1) t_hi = NT - 1;
    if (t_hi - t_lo == 3) {
        const float* __restrict__ fp = frames + (b * NT + t_lo) * NFFT + (i - (t_lo << 7));
        const float acc = fp[0] + fp[384] + fp[768] + fp[1152];
        out[j] = acc * (2.0f / 3.0f);
    } else {
        float acc = 0.0f, wacc = 0.0f;
        for (int t = t_lo; t <= t_hi; ++t) {
            const int n = i - (t << 7);
            const float w = hann(n);
            acc  += frames[(b * NT + t) * NFFT + n];
            wacc += w * w;
        }
        out[j] = acc / fmaxf(wacc, 1e-11f);
    }
}

extern "C" void kernel_launch(void* const* d_in, const int* in_sizes, int n_in,
                              void* d_out, int out_size, void* d_ws, size_t ws_size,
                              hipStream_t stream) {
    const float* noisy    = (const float*)d_in[0];
    const float* enhanced = (const float*)d_in[1];
    float* out = (float*)d_out;

    // workspace layout (floats), total 25680528 (~102.7 MB):
    //   e_spec : [0, 10288224)              (16*1251*257 float2)
    //   floor  : [10288224, 15432336)
    //   n_mag  : [15432336, 20576448)       (dead after floor_kernel)
    //   frames : [15432336, 25680528)       (reuses dead n_mag region)
    float* ws = (float*)d_ws;
    float2* e_spec = (float2*)ws;
    float* floor_ = ws + 10288224;
    float* n_mag  = ws + 15432336;
    float* frames = ws + 15432336;

    dim3 blk(256);
    stft_kernel <<<dim3((NT + 3) / 4, BATCH), blk, 0, stream>>>(enhanced, noisy, e_spec, n_mag);
    floor_kernel<<<dim3((NT + 15) / 16, BATCH), blk, 0, stream>>>(n_mag, floor_);
    istft_kernel<<<dim3((NT + 7) / 8, BATCH), blk, 0, stream>>>(e_spec, floor_, frames);
    ola_kernel  <<<dim3((BATCH * LEN + 255) / 256), blk, 0, stream>>>(frames, out);
}